// Round 6
// baseline (24234.583 us; speedup 1.0000x reference)
//
#include <hip/hip_runtime.h>

#define EPS 1e-5f

__device__ __forceinline__ float logsig(float z) {
    return fminf(z, 0.0f) - log1pf(__expf(-fabsf(z)));
}

// R6: two 256-thread blocks per CU (was one 512-thread block).
// Same 8 waves/CU, but the two blocks share no barriers -> when one drains,
// the other's waves keep the SIMDs busy. Empirical RA law (R0/R1/R2):
// VGPR cap = 2048/(2*waves_per_wg) -> 256 thr = 256 VGPRs/thread, which
// enables: wave = head, S[64]/thread (no kh split, F2a phase gone),
// v & r in registers (voc v-role gone), scores in regs consumed via
// compile-time shfl (Ats LDS gone), full-column gate cumsum (carry barrier
// gone). LDS 148KB -> 76KB so 2 blocks fit. Barriers 12 -> 7 per chunk.
// Region reuse: qfR = {smu/sinv (B-phase)} -> qf -> o ;
//               kfR = {fw1t (gate phase)} -> kf -> gdec.
// Residual re-read from global at I (sxr dropped; src is never overwritten).
template<int SLEN, int PSTRIDE>
__global__ __launch_bounds__(256, 2)
void gla_pass(const float* __restrict__ src, float* __restrict__ out,
              const float* __restrict__ gamma, const float* __restrict__ beta,
              const float* __restrict__ Wq, const float* __restrict__ Wk,
              const float* __restrict__ Wv, const float* __restrict__ Wg1,
              const float* __restrict__ Wg2, const float* __restrict__ Wr,
              const float* __restrict__ gn, const float* __restrict__ Wo,
              const float* __restrict__ ctw, const float* __restrict__ ctb)
{
    constexpr int NC = SLEN / 32;
    constexpr int L  = SLEN - 1;

    __shared__ __align__(16) float sx[64][36];      // slab, 33 cols used (single buffer;
                                                    // next chunk rides in pre[] regs)
    __shared__ __align__(16) float qfR[32 * 260];   // smu/sinv -> qf -> o
    __shared__ __align__(16) float kfR[32 * 260];   // fw1t -> kf -> gdec
    __shared__ float egl[256];                      // exp(chunk-total gate)
    __shared__ float gprevs[128];                   // deconv carry row
    __shared__ float sgam[64], sbet[64];

    const int tid  = threadIdx.x;     // 0..255 ; also projection column d
    const int lane = tid & 63;
    const int h    = tid >> 6;        // wave = head
    const int base = h * 64;
    const int n    = blockIdx.x;

    int b, fixedoff;
    if constexpr (PSTRIDE == 1) { b = n >> 8; fixedoff = (n & 255) * 128; }
    else                        { b = n >> 7; fixedoff = (n & 127); }
    const int cbase = (b * 64) * 32768 + fixedoff;

    if (tid < 64)  { sgam[tid] = gamma[tid]; sbet[tid] = beta[tid]; }
    if (tid < 128) gprevs[tid] = 0.0f;

    float S[64];
    #pragma unroll
    for (int k = 0; k < 64; ++k) S[k] = 0.0f;

    const float gnv  = gn[base + lane];
    const int   oc   = tid & 63;      // I-stage: output channel
    const int   pg   = tid >> 6;      // I-stage: row group (8 rows)
    const float bias = ctb[oc];

    // ---- prologue: chunk-0 slab ----
    #pragma unroll
    for (int k = 0; k < 9; ++k) {
        int idx = tid + k * 256;
        if (idx < 2112) {
            int cc = idx / 33, i = idx - cc * 33;
            sx[cc][i] = src[cbase + cc * 32768 + i * PSTRIDE];
        }
    }

    for (int ch = 0; ch < NC; ++ch) {
        const int l0 = ch * 32;
        __syncthreads();                       // S1: sx(ch) raw ready; prev chunk done

        // ---- A': next-chunk slab -> regs (written to sx after G) ----
        float pre[9];
        const bool pf = (ch + 1 < NC);
        if (pf) {
            #pragma unroll
            for (int k = 0; k < 9; ++k) {
                int idx = tid + k * 256;
                if (idx < 2112) {
                    int cc = idx / 33, i = idx - cc * 33;
                    int p = l0 + 32 + i; if (p > SLEN - 1) p = SLEN - 1;
                    pre[k] = src[cbase + cc * 32768 + p * PSTRIDE];
                }
            }
        }

        // ---- B1: LN stats (wave tree); deconv-carry copy (gdec(ch-1) row 31) ----
        if (ch > 0 && tid < 128) gprevs[tid] = kfR[31 * 260 + tid];
        for (int col = h; col < 33; col += 4) {
            float x = sx[lane][col];
            float s1 = x, s2 = x * x;
            #pragma unroll
            for (int off = 32; off > 0; off >>= 1) {
                s1 += __shfl_xor(s1, off, 64);
                s2 += __shfl_xor(s2, off, 64);
            }
            if (lane == 0) {
                float mu  = s1 * (1.0f / 64.0f);
                float var = s2 * (1.0f / 64.0f) - mu * mu;
                qfR[col]      = mu;                              // smu
                qfR[64 + col] = rsqrtf(fmaxf(var, 0.0f) + EPS);  // sinv
            }
        }
        __syncthreads();                       // S2

        // ---- B2: normalize in place ----
        #pragma unroll
        for (int k = 0; k < 9; ++k) {
            int idx = tid + k * 256;
            if (idx < 2112) {
                int cc = idx / 33, i = idx - cc * 33;
                sx[cc][i] = (sx[cc][i] - qfR[i]) * qfR[64 + i] * sgam[cc] + sbet[cc];
            }
        }
        __syncthreads();                       // S3

        // ---- p1: fw1t[m][t] (into kfR rows, stride 260) ----
        {
            const int m = tid & 31, tg = tid >> 5;    // t = tg*4 + k
            float a0 = 0, a1 = 0, a2 = 0, a3 = 0;
            for (int cc = 0; cc < 64; ++cc) {
                float w0 = Wg1[(2*cc)*32 + m], w1 = Wg1[(2*cc+1)*32 + m];
                float4 c4 = *(const float4*)&sx[cc][tg * 4];
                float  c1 = sx[cc][tg * 4 + 4];
                a0 += c4.x*w0 + c4.y*w1;
                a1 += c4.y*w0 + c4.z*w1;
                a2 += c4.z*w0 + c4.w*w1;
                a3 += c4.w*w0 + c1  *w1;
            }
            kfR[m*260 + tg*4 + 0] = a0;
            kfR[m*260 + tg*4 + 1] = a1;
            kfR[m*260 + tg*4 + 2] = a2;
            kfR[m*260 + tg*4 + 3] = a3;
        }
        __syncthreads();                       // S4

        // ---- p2: full-column gate log-cumsum (no carry exchange) ----
        float rn[32];
        {
            float acc[32];
            #pragma unroll
            for (int t = 0; t < 32; ++t) acc[t] = 0.0f;
            for (int mm = 0; mm < 32; ++mm) {
                float w = Wg2[mm * 256 + tid];
                #pragma unroll
                for (int i = 0; i < 8; ++i) {
                    float4 f4 = *(const float4*)&kfR[mm*260 + 4*i];
                    acc[4*i+0] += f4.x * w; acc[4*i+1] += f4.y * w;
                    acc[4*i+2] += f4.z * w; acc[4*i+3] += f4.w * w;
                }
            }
            float r = 0.0f;
            #pragma unroll
            for (int t = 0; t < 32; ++t) {
                if (l0 + t < L) r += logsig(acc[t]) * (1.0f / 32.0f);
                rn[t] = r;
            }
            egl[tid] = __expf(rn[31]);
        }
        __syncthreads();                       // S5 (fw1t reads done before kf writes)

        // ======== sync-free stretch: C1q, C1k, C2(v,r), F1, F2, F4, G ========
        // (qf/kf/egl traffic is head-column-local = same-wave; LDS ops within a
        //  wave are ordered by the compiler's conservative lgkmcnt waits.)

        // ---- C1q: q projection, gate exp folded at store ----
        {
            float aq[32];
            #pragma unroll
            for (int t = 0; t < 32; ++t) aq[t] = 0.0f;
            for (int cc = 0; cc < 64; ++cc) {
                float w0 = Wq[(2*cc)*256 + tid], w1 = Wq[(2*cc+1)*256 + tid];
                float col[33];
                #pragma unroll
                for (int i = 0; i < 8; ++i) {
                    float4 c4 = *(const float4*)&sx[cc][4*i];
                    col[4*i]=c4.x; col[4*i+1]=c4.y; col[4*i+2]=c4.z; col[4*i+3]=c4.w;
                }
                col[32] = sx[cc][32];
                #pragma unroll
                for (int t = 0; t < 32; ++t) aq[t] += col[t]*w0 + col[t+1]*w1;
            }
            #pragma unroll
            for (int t = 0; t < 32; ++t)
                qfR[t*260 + tid] = (l0 + t < L) ? aq[t] * 0.125f * __expf(rn[t]) : 0.0f;
        }
        // ---- C1k: k projection ----
        {
            float ak[32];
            #pragma unroll
            for (int t = 0; t < 32; ++t) ak[t] = 0.0f;
            for (int cc = 0; cc < 64; ++cc) {
                float w0 = Wk[(2*cc)*256 + tid], w1 = Wk[(2*cc+1)*256 + tid];
                float col[33];
                #pragma unroll
                for (int i = 0; i < 8; ++i) {
                    float4 c4 = *(const float4*)&sx[cc][4*i];
                    col[4*i]=c4.x; col[4*i+1]=c4.y; col[4*i+2]=c4.z; col[4*i+3]=c4.w;
                }
                col[32] = sx[cc][32];
                #pragma unroll
                for (int t = 0; t < 32; ++t) ak[t] += col[t]*w0 + col[t+1]*w1;
            }
            #pragma unroll
            for (int t = 0; t < 32; ++t)
                kfR[t*260 + tid] = (l0 + t < L) ? ak[t] * __expf(-rn[t]) : 0.0f;
        }
        // ---- C2: v & r fused; both stay in registers ----
        float av[32], ar[32];
        {
            #pragma unroll
            for (int t = 0; t < 32; ++t) { av[t] = 0.0f; ar[t] = 0.0f; }
            for (int cc = 0; cc < 64; ++cc) {
                float wv0 = Wv[(2*cc)*256 + tid], wv1 = Wv[(2*cc+1)*256 + tid];
                float wr0 = Wr[(2*cc)*256 + tid], wr1 = Wr[(2*cc+1)*256 + tid];
                float col[33];
                #pragma unroll
                for (int i = 0; i < 8; ++i) {
                    float4 c4 = *(const float4*)&sx[cc][4*i];
                    col[4*i]=c4.x; col[4*i+1]=c4.y; col[4*i+2]=c4.z; col[4*i+3]=c4.w;
                }
                col[32] = sx[cc][32];
                #pragma unroll
                for (int t = 0; t < 32; ++t) {
                    av[t] += col[t]*wv0 + col[t+1]*wv1;
                    ar[t] += col[t]*wr0 + col[t+1]*wr1;
                }
            }
            #pragma unroll
            for (int t = 0; t < 32; ++t) if (l0 + t >= L) av[t] = 0.0f;
        }

        // ---- F1: triangular scores into registers (pair pi -> lane pi&63, reg pi>>6) ----
        float a[9];
        #pragma unroll
        for (int j = 0; j < 9; ++j) a[j] = 0.0f;
        #pragma unroll
        for (int j = 0; j < 9; ++j) {
            int pi = lane + 64 * j;
            if (pi < 528) {
                float fpi = (float)pi;
                int t = (int)((sqrtf(8.0f * fpi + 1.0f) - 1.0f) * 0.5f);
                if (((t + 1) * (t + 2)) / 2 <= pi) ++t;
                if ((t * (t + 1)) / 2 > pi) --t;
                int s = pi - (t * (t + 1)) / 2;
                float acc = 0.0f;
                #pragma unroll
                for (int ii = 0; ii < 16; ++ii) {
                    int i = (ii + lane) & 15;
                    float4 q4 = *(const float4*)&qfR[t*260 + base + 4*i];
                    float4 k4 = *(const float4*)&kfR[s*260 + base + 4*i];
                    acc += q4.x*k4.x + q4.y*k4.y + q4.z*k4.z + q4.w*k4.w;
                }
                a[j] = acc;
            }
        }

        // ---- F2: o = q@S (dk 0..63) + A@v (shfl) ; RMS-norm ; write into qfR row t ----
        #pragma unroll
        for (int t = 0; t < 32; ++t) {
            float ot = 0.0f;
            #pragma unroll
            for (int i = 0; i < 16; ++i) {
                float4 q4 = *(const float4*)&qfR[t*260 + base + 4*i];
                ot += q4.x*S[4*i] + q4.y*S[4*i+1] + q4.z*S[4*i+2] + q4.w*S[4*i+3];
            }
            #pragma unroll
            for (int s = 0; s <= t; ++s) {
                const int pi = (t * (t + 1)) / 2 + s;
                ot += __shfl(a[pi >> 6], pi & 63, 64) * av[s];
            }
            float ss = ot * ot;
            #pragma unroll
            for (int off = 32; off > 0; off >>= 1) ss += __shfl_xor(ss, off, 64);
            qfR[t*260 + base + lane] = ot * rsqrtf(ss * (1.0f / 64.0f) + EPS) * gnv;
        }

        // ---- F4: S update, all 64 rows ----
        #pragma unroll
        for (int i = 0; i < 16; ++i) {
            float s0 = 0, s1 = 0, s2 = 0, s3 = 0;
            #pragma unroll
            for (int t = 0; t < 32; ++t) {
                float4 k4 = *(const float4*)&kfR[t*260 + base + 4*i];
                float vt = av[t];
                s0 += k4.x*vt; s1 += k4.y*vt; s2 += k4.z*vt; s3 += k4.w*vt;
            }
            S[4*i+0] = egl[base + 4*i+0] * (S[4*i+0] + s0);
            S[4*i+1] = egl[base + 4*i+1] * (S[4*i+1] + s1);
            S[4*i+2] = egl[base + 4*i+2] * (S[4*i+2] + s2);
            S[4*i+3] = egl[base + 4*i+3] * (S[4*i+3] + s3);
        }

        // ---- G: o *= silu(r) (own column; r from regs) ----
        #pragma unroll
        for (int t = 0; t < 32; ++t) {
            float r = ar[t];
            qfR[t*260 + tid] *= r / (1.0f + __expf(-r));
        }
        __syncthreads();                       // S6: o complete (cross-head for H)

        // ---- A'': write prefetched slab (sx dead since G) ----
        if (pf) {
            #pragma unroll
            for (int k = 0; k < 9; ++k) {
                int idx = tid + k * 256;
                if (idx < 2112) {
                    int cc = idx / 33, i = idx - cc * 33;
                    sx[cc][i] = pre[k];
                }
            }
        }
        // ---- residual preload for I (issued early; hides under H) ----
        float resid[8];
        #pragma unroll
        for (int r2 = 0; r2 < 8; ++r2)
            resid[r2] = src[cbase + oc * 32768 + (l0 + pg * 8 + r2) * PSTRIDE];

        // ---- H: gdec = o @ Wo (into kfR rows; kf dead after F4) ----
        {
            const int m2 = tid & 127, rh = tid >> 7;   // rows rh*16 .. +15
            float acc[16];
            #pragma unroll
            for (int r2 = 0; r2 < 16; ++r2) acc[r2] = 0.0f;
            for (int jb = 0; jb < 64; ++jb) {
                float w0 = Wo[(4*jb+0)*128 + m2];
                float w1 = Wo[(4*jb+1)*128 + m2];
                float w2 = Wo[(4*jb+2)*128 + m2];
                float w3 = Wo[(4*jb+3)*128 + m2];
                #pragma unroll
                for (int r2 = 0; r2 < 16; ++r2) {
                    float4 o4 = *(const float4*)&qfR[(rh*16 + r2)*260 + 4*jb];
                    acc[r2] += o4.x*w0 + o4.y*w1 + o4.z*w2 + o4.w*w3;
                }
            }
            #pragma unroll
            for (int r2 = 0; r2 < 16; ++r2)
                kfR[(rh*16 + r2)*260 + m2] = acc[r2];
        }
        __syncthreads();                       // S7: gdec ready

        // ---- I: deconv1d (K=2) + bias + residual + store (8 rows/thread) ----
        {
            const float2* ctw2 = (const float2*)ctw;   // [cin][oc] -> (w_k0, w_k1)
            float acc8[8];
            #pragma unroll
            for (int r2 = 0; r2 < 8; ++r2) acc8[r2] = 0.0f;
            for (int c4 = 0; c4 < 128; c4 += 4) {
                float2 w0 = ctw2[(c4+0)*64 + oc];
                float2 w1 = ctw2[(c4+1)*64 + oc];
                float2 w2 = ctw2[(c4+2)*64 + oc];
                float2 w3 = ctw2[(c4+3)*64 + oc];
                float4 rm = (pg == 0) ? *(const float4*)&gprevs[c4]
                                      : *(const float4*)&kfR[(pg*8 - 1)*260 + c4];
                #pragma unroll
                for (int r2 = 0; r2 < 8; ++r2) {
                    float4 rr = *(const float4*)&kfR[(pg*8 + r2)*260 + c4];
                    acc8[r2] += rr.x*w0.x + rm.x*w0.y
                              + rr.y*w1.x + rm.y*w1.y
                              + rr.z*w2.x + rm.z*w2.y
                              + rr.w*w3.x + rm.w*w3.y;
                    rm = rr;
                }
            }
            #pragma unroll
            for (int r2 = 0; r2 < 8; ++r2)
                out[cbase + oc * 32768 + (l0 + pg * 8 + r2) * PSTRIDE]
                    = acc8[r2] + bias + resid[r2];
        }
    }
}

extern "C" void kernel_launch(void* const* d_in, const int* in_sizes, int n_in,
                              void* d_out, int out_size, void* d_ws, size_t ws_size,
                              hipStream_t stream)
{
    const float* x = (const float*)d_in[0];
    float* y = (float*)d_ws;     // intra output: 4*64*256*128 fp32
    float* z = (float*)d_out;

    gla_pass<128, 1><<<dim3(1024), dim3(256), 0, stream>>>(
        x, y,
        (const float*)d_in[2],  (const float*)d_in[3],  (const float*)d_in[4],
        (const float*)d_in[5],  (const float*)d_in[6],  (const float*)d_in[7],
        (const float*)d_in[8],  (const float*)d_in[9],  (const float*)d_in[10],
        (const float*)d_in[11], (const float*)d_in[12], (const float*)d_in[13]);

    gla_pass<256, 128><<<dim3(512), dim3(256), 0, stream>>>(
        y, z,
        (const float*)d_in[14], (const float*)d_in[15], (const float*)d_in[16],
        (const float*)d_in[17], (const float*)d_in[18], (const float*)d_in[19],
        (const float*)d_in[20], (const float*)d_in[21], (const float*)d_in[22],
        (const float*)d_in[23], (const float*)d_in[24], (const float*)d_in[25]);
}

// Round 7
// 7461.967 us; speedup vs baseline: 3.2477x; 3.2477x over previous
//
#include <hip/hip_runtime.h>

#define EPS 1e-5f

__device__ __forceinline__ float logsig(float z) {
    return fminf(z, 0.0f) - log1pf(__expf(-fabsf(z)));
}

// Weight pre-pack (per launch). Layout per pass (float offsets from pack base):
//   [0,     65536)  pWqk[cc*256+d] = {Wq[2cc][d], Wq[2cc+1][d], Wk[2cc][d], Wk[2cc+1][d]}
//   [65536,131072)  pWvr[cc*256+d] = {Wv[2cc][d], Wv[2cc+1][d], Wr[2cc][d], Wr[2cc+1][d]}
//   [131072,135168) pWg1[cc*32+m]  = {Wg1[2cc][m], Wg1[2cc+1][m]}
//   [135168,167936) WoT4[m2*64+jb] = {Wo[4jb][m2], Wo[4jb+1][m2], Wo[4jb+2][m2], Wo[4jb+3][m2]}
__global__ __launch_bounds__(256)
void pack_weights(const float* __restrict__ Wq0, const float* __restrict__ Wk0,
                  const float* __restrict__ Wv0, const float* __restrict__ Wr0,
                  const float* __restrict__ Wg10, const float* __restrict__ Wo0,
                  const float* __restrict__ Wq1, const float* __restrict__ Wk1,
                  const float* __restrict__ Wv1, const float* __restrict__ Wr1,
                  const float* __restrict__ Wg11, const float* __restrict__ Wo1,
                  float* __restrict__ pk)
{
    int idx = blockIdx.x * 256 + threadIdx.x;      // [0, 86016)
    int p   = (idx >= 43008) ? 1 : 0;
    int j   = idx - p * 43008;                     // 16384+16384+2048+8192
    const float* Wq  = p ? Wq1  : Wq0;
    const float* Wk  = p ? Wk1  : Wk0;
    const float* Wv  = p ? Wv1  : Wv0;
    const float* Wr  = p ? Wr1  : Wr0;
    const float* Wg1 = p ? Wg11 : Wg10;
    const float* Wo  = p ? Wo1  : Wo0;
    float* base = pk + p * 167936;
    if (j < 16384) {
        int cc = j >> 8, d = j & 255;
        float4 v = { Wq[(2*cc)*256 + d], Wq[(2*cc+1)*256 + d],
                     Wk[(2*cc)*256 + d], Wk[(2*cc+1)*256 + d] };
        ((float4*)base)[j] = v;
    } else if (j < 32768) {
        int jj = j - 16384;
        int cc = jj >> 8, d = jj & 255;
        float4 v = { Wv[(2*cc)*256 + d], Wv[(2*cc+1)*256 + d],
                     Wr[(2*cc)*256 + d], Wr[(2*cc+1)*256 + d] };
        ((float4*)(base + 65536))[jj] = v;
    } else if (j < 34816) {
        int jj = j - 32768;
        int cc = jj >> 5, m = jj & 31;
        float2 v = { Wg1[(2*cc)*32 + m], Wg1[(2*cc+1)*32 + m] };
        ((float2*)(base + 131072))[jj] = v;
    } else {
        int jj = j - 34816;                        // [0, 8192)
        int m2 = jj >> 6, jb = jj & 63;
        float4 v = { Wo[(4*jb+0)*128 + m2], Wo[(4*jb+1)*128 + m2],
                     Wo[(4*jb+2)*128 + m2], Wo[(4*jb+3)*128 + m2] };
        ((float4*)(base + 135168))[jj] = v;
    }
}

// One block = one sequence. 512 threads = 8 waves.
// Head h = wave&3; k-half kh = wave>>2. PSTRIDE==1: intra (SLEN=128);
// PSTRIDE==128: inter (SLEN=256).
// Hard constraint (R0/R1/R2/R6): the backend caps VGPRs at 128 for any block
// shape regardless of launch_bounds/waves_per_eu attributes -> every design
// must fit 128 regs. 512 threads, 1 block/CU (LDS ~148KB).
// R3: slab double-buffer + reg prefetch, wave-parallel LN, Ats/gdec overlay.
// R7: (a) q,k,v fused in ONE slab pass, 2 sub-passes of 8 t's (live regs ~95,
//     av dies at its store -> no R4-style spill); (b) voc stride 260 -> H's
//     8-way row bank conflicts eliminated; (c) H remapped 2rowsx4cols with
//     transposed-Wo float4 loads (LDS reads halved).
template<int SLEN, int PSTRIDE>
__global__ __launch_bounds__(512)
void gla_pass(const float* __restrict__ src, float* __restrict__ out,
              const float* __restrict__ gamma, const float* __restrict__ beta,
              const float4* __restrict__ pWqk, const float4* __restrict__ pWvr,
              const float2* __restrict__ pWg1, const float4* __restrict__ WoT4,
              const float* __restrict__ Wg2,
              const float* __restrict__ gn,
              const float* __restrict__ ctw, const float* __restrict__ ctb)
{
    constexpr int NC = SLEN / 32;
    constexpr int L  = SLEN - 1;

    __shared__ __align__(16) float sxA[64][36];   // slab buffer A (33 cols used)
    __shared__ __align__(16) float sxB[64][36];   // slab buffer B
    __shared__ __align__(16) float sxr[64][32];   // raw slab (residual source)
    __shared__ __align__(16) float qf[32][256];   // q*Dk^-0.5 * exp(gc)
    __shared__ __align__(16) float kf[32][256];   // k * exp(-gc)
    __shared__ __align__(16) float voc[32][260];  // stride 260: rows spread banks
    __shared__ __align__(16) float uni[4608];     // Ats OVERLAID with gdec[32][132]
    __shared__ __align__(16) float fw1t[32][36];  // (f @ Wg1)^T
    __shared__ __align__(16) float gprevs[128];   // deconv carry row
    __shared__ float egl[256];                    // exp(chunk-total gate)
    __shared__ float sgam[64], sbet[64];
    __shared__ float smu[33], sinv[33];
    __shared__ float gcarry[256];                 // gate cumsum carry

    float* const Ats  = uni;          // h*1152 + t*36 + s   (live F1 -> F2b)
    float* const gdec = uni;          // row*132 + c         (live H -> I)

    const int tid  = threadIdx.x;
    const int lane = tid & 63;
    const int wv   = tid >> 6;        // 0..7
    const int h    = wv & 3;          // head
    const int kh   = wv >> 2;         // k-half
    const int d    = tid & 255;       // column for t-split stages
    const int th   = (tid >> 8) & 1;  // t-half; th == kh
    const int n    = blockIdx.x;

    int b, fixedoff;
    if constexpr (PSTRIDE == 1) { b = n >> 8; fixedoff = (n & 255) * 128; }
    else                        { b = n >> 7; fixedoff = (n & 127); }
    const int cbase = (b * 64) * 32768 + fixedoff;

    if (tid < 64)  { sgam[tid] = gamma[tid]; sbet[tid] = beta[tid]; }
    if (tid < 128) gprevs[tid] = 0.0f;

    float S[32];
    #pragma unroll
    for (int k = 0; k < 32; ++k) S[k] = 0.0f;

    const float gnv  = gn[h * 64 + lane];
    const float bias = ctb[lane];

    // ---- prologue: chunk-0 slab -> sxA (raw) ----
    #pragma unroll
    for (int k = 0; k < 5; ++k) {
        int idx = tid + k * 512;
        if (idx < 64 * 33) {
            int cc = idx / 33, i = idx - cc * 33;
            sxA[cc][i] = src[cbase + cc * 32768 + i * PSTRIDE];
        }
    }

    for (int ch = 0; ch < NC; ++ch) {
        const int l0 = ch * 32;
        float (* const cur)[36] = (ch & 1) ? sxB : sxA;
        float (* const nxt)[36] = (ch & 1) ? sxA : sxB;
        __syncthreads();              // cur(ch) raw ready

        // ---- A': next-chunk slab -> regs (written to nxt after gate) ----
        float pre[5];
        const bool pf = (ch + 1 < NC);
        if (pf) {
            const int l0n = l0 + 32;
            #pragma unroll
            for (int k = 0; k < 5; ++k) {
                int idx = tid + k * 512;
                if (idx < 64 * 33) {
                    int cc = idx / 33, i = idx - cc * 33;
                    int p  = l0n + i; if (p > SLEN - 1) p = SLEN - 1;
                    pre[k] = src[cbase + cc * 32768 + p * PSTRIDE];
                }
            }
        }

        // ---- B1: per-column LN stats, wave-parallel (R3 form) ----
        for (int col = wv; col < 33; col += 8) {
            float x = cur[lane][col];
            float s1 = x, s2 = x * x;
            #pragma unroll
            for (int off = 32; off > 0; off >>= 1) {
                s1 += __shfl_xor(s1, off, 64);
                s2 += __shfl_xor(s2, off, 64);
            }
            if (lane == 0) {
                float mu  = s1 * (1.0f / 64.0f);
                float var = s2 * (1.0f / 64.0f) - mu * mu;
                smu[col]  = mu;
                sinv[col] = rsqrtf(fmaxf(var, 0.0f) + EPS);
            }
        }
        __syncthreads();

        // ---- B2: normalize in place, raw copy to sxr fused ----
        #pragma unroll
        for (int k = 0; k < 5; ++k) {
            int idx = tid + k * 512;
            if (idx < 64 * 33) {
                int cc = idx / 33, i = idx - cc * 33;
                float x = cur[cc][i];
                if (i < 32) sxr[cc][i] = x;
                cur[cc][i] = (x - smu[i]) * sinv[i] * sgam[cc] + sbet[cc];
            }
        }
        __syncthreads();

        // ---- gate p1: fw1t[m][t] (packed float2 weights) ----
        {
            const int m = tid & 31, tg2 = tid >> 5;   // tg2 in [0,16)
            float a0 = 0.0f, a1 = 0.0f;
            #pragma unroll 2
            for (int cc = 0; cc < 64; ++cc) {
                float2 wg = pWg1[cc * 32 + m];
                a0 += cur[cc][tg2]      * wg.x + cur[cc][tg2 + 1]  * wg.y;
                a1 += cur[cc][tg2 + 16] * wg.x + cur[cc][tg2 + 17] * wg.y;
            }
            fw1t[m][tg2] = a0; fw1t[m][tg2 + 16] = a1;
        }
        __syncthreads();

        // ---- gate p2: per (col d, t-half) cumsum with carry -> rn[16] ----
        float rn[16];
        {
            const int t0 = th * 16;
            float acc2[16];
            #pragma unroll
            for (int t = 0; t < 16; ++t) acc2[t] = 0.0f;
            for (int mm = 0; mm < 32; ++mm) {
                const float w = Wg2[mm * 256 + d];
                #pragma unroll
                for (int i = 0; i < 4; ++i) {
                    float4 f4 = *(const float4*)&fw1t[mm][t0 + 4 * i];
                    acc2[4*i+0] += f4.x * w; acc2[4*i+1] += f4.y * w;
                    acc2[4*i+2] += f4.z * w; acc2[4*i+3] += f4.w * w;
                }
            }
            float r = 0.0f;
            #pragma unroll
            for (int t = 0; t < 16; ++t) {
                if ((l0 + t0 + t) < L) r += logsig(acc2[t]) * (1.0f / 32.0f);
                acc2[t] = r;
            }
            if (th == 0) gcarry[d] = r;
            __syncthreads();
            const float c = (th == 0) ? 0.0f : gcarry[d];
            #pragma unroll
            for (int t = 0; t < 16; ++t) rn[t] = c + acc2[t];
            if (th == 1) egl[d] = __expf(rn[15]);
        }

        // ---- A'': write prefetched slab into nxt ----
        if (pf) {
            #pragma unroll
            for (int k = 0; k < 5; ++k) {
                int idx = tid + k * 512;
                if (idx < 64 * 33) {
                    int cc = idx / 33, i = idx - cc * 33;
                    nxt[cc][i] = pre[k];
                }
            }
        }

        // ---- C: q,k,v fused in ONE slab pass; two 8-t sub-passes ----
        #pragma unroll
        for (int p = 0; p < 2; ++p) {
            const int t0 = th * 16 + p * 8;
            float aq[8], ak[8], av[8];
            #pragma unroll
            for (int t = 0; t < 8; ++t) { aq[t] = 0.0f; ak[t] = 0.0f; av[t] = 0.0f; }
            for (int cc = 0; cc < 64; ++cc) {
                float col[9];
                float4 c4 = *(const float4*)&cur[cc][t0];
                float4 c5 = *(const float4*)&cur[cc][t0 + 4];
                col[0]=c4.x; col[1]=c4.y; col[2]=c4.z; col[3]=c4.w;
                col[4]=c5.x; col[5]=c5.y; col[6]=c5.z; col[7]=c5.w;
                col[8]=cur[cc][t0 + 8];
                float4 wqk = pWqk[cc * 256 + d];
                float4 wvr = pWvr[cc * 256 + d];
                #pragma unroll
                for (int t = 0; t < 8; ++t) {
                    aq[t] += col[t] * wqk.x + col[t+1] * wqk.y;
                    ak[t] += col[t] * wqk.z + col[t+1] * wqk.w;
                    av[t] += col[t] * wvr.x + col[t+1] * wvr.y;
                }
            }
            #pragma unroll
            for (int t = 0; t < 8; ++t) {
                const int tt = t0 + t;
                bool valid = (l0 + tt) < L;
                float r = rn[p * 8 + t];
                qf[tt][d]  = valid ? aq[t] * 0.125f * __expf(r) : 0.0f;
                kf[tt][d]  = valid ? ak[t] * __expf(-r) : 0.0f;
                voc[tt][d] = valid ? av[t] : 0.0f;
            }
        }
        __syncthreads();

        // ---- F: attention; 2 waves per head ----
        const int base = h * 64;
        float vcol[32];
        #pragma unroll
        for (int t = 0; t < 32; ++t) vcol[t] = voc[t][base + lane];

        // F1: triangular scores, 128 lanes per head
        for (int pi = lane + 64 * kh; pi < 528; pi += 128) {
            float fpi = (float)pi;
            int t = (int)((sqrtf(8.0f * fpi + 1.0f) - 1.0f) * 0.5f);
            if (((t + 1) * (t + 2)) / 2 <= pi) ++t;
            if ((t * (t + 1)) / 2 > pi) --t;
            int s = pi - (t * (t + 1)) / 2;
            float a = 0.0f;
            #pragma unroll
            for (int ii = 0; ii < 16; ++ii) {
                int i = (ii + lane) & 15;
                float4 q4 = *(const float4*)&qf[t][base + 4 * i];
                float4 k4 = *(const float4*)&kf[s][base + 4 * i];
                a += q4.x*k4.x + q4.y*k4.y + q4.z*k4.z + q4.w*k4.w;
            }
            Ats[h * 1152 + t * 36 + s] = a;
        }
        __syncthreads();   // A: Ats ready; vcol snapped (voc dead as v)

        // F2a: kh1 writes o_inter partial (pre-update S rows 32..63) into voc
        if (kh == 1) {
            #pragma unroll
            for (int t = 0; t < 32; ++t) {
                float oe = 0.0f;
                #pragma unroll
                for (int i = 0; i < 8; ++i) {
                    float4 q4 = *(const float4*)&qf[t][base + 32 + 4 * i];
                    oe += q4.x*S[4*i] + q4.y*S[4*i+1] + q4.z*S[4*i+2] + q4.w*S[4*i+3];
                }
                voc[t][base + lane] = oe;
            }
        }
        __syncthreads();   // B: oe1 partials in voc

        if (kh == 0) {
            // F2b: o = oe0 + oe1 + o_intra, RMS-norm, final o into voc
            #pragma unroll
            for (int t = 0; t < 32; ++t) {
                float ot = voc[t][base + lane];
                #pragma unroll
                for (int i = 0; i < 8; ++i) {
                    float4 q4 = *(const float4*)&qf[t][base + 4 * i];
                    ot += q4.x*S[4*i] + q4.y*S[4*i+1] + q4.z*S[4*i+2] + q4.w*S[4*i+3];
                }
                const float* arow = &Ats[h * 1152 + t * 36];
                #pragma unroll
                for (int s4 = 0; s4 + 4 <= t + 1; s4 += 4) {
                    float4 a4 = *(const float4*)&arow[s4];
                    ot += a4.x*vcol[s4] + a4.y*vcol[s4+1] + a4.z*vcol[s4+2] + a4.w*vcol[s4+3];
                }
                #pragma unroll
                for (int s = (t + 1) & ~3; s <= t; ++s) ot += arow[s] * vcol[s];
                float ss = ot * ot;
                #pragma unroll
                for (int off = 32; off > 0; off >>= 1) ss += __shfl_xor(ss, off, 64);
                voc[t][base + lane] = ot * rsqrtf(ss * (1.0f / 64.0f) + EPS) * gnv;
            }
        } else {
            // kh1: F4 state update rows 32..63
            const int kb = base + 32;
            #pragma unroll
            for (int i = 0; i < 8; ++i) {
                float s0 = 0.0f, s1 = 0.0f, s2 = 0.0f, s3 = 0.0f;
                #pragma unroll
                for (int t = 0; t < 32; ++t) {
                    float4 k4 = *(const float4*)&kf[t][kb + 4 * i];
                    const float vt = vcol[t];
                    s0 += k4.x * vt; s1 += k4.y * vt; s2 += k4.z * vt; s3 += k4.w * vt;
                }
                S[4*i+0] = egl[kb + 4*i+0] * (S[4*i+0] + s0);
                S[4*i+1] = egl[kb + 4*i+1] * (S[4*i+1] + s1);
                S[4*i+2] = egl[kb + 4*i+2] * (S[4*i+2] + s2);
                S[4*i+3] = egl[kb + 4*i+3] * (S[4*i+3] + s3);
            }
        }
        __syncthreads();   // C: final o in voc

        if (kh == 0) {
            // F4 state update rows 0..31 (overlaps kh1's half of G)
            const int kb = base;
            #pragma unroll
            for (int i = 0; i < 8; ++i) {
                float s0 = 0.0f, s1 = 0.0f, s2 = 0.0f, s3 = 0.0f;
                #pragma unroll
                for (int t = 0; t < 32; ++t) {
                    float4 k4 = *(const float4*)&kf[t][kb + 4 * i];
                    const float vt = vcol[t];
                    s0 += k4.x * vt; s1 += k4.y * vt; s2 += k4.z * vt; s3 += k4.w * vt;
                }
                S[4*i+0] = egl[kb + 4*i+0] * (S[4*i+0] + s0);
                S[4*i+1] = egl[kb + 4*i+1] * (S[4*i+1] + s1);
                S[4*i+2] = egl[kb + 4*i+2] * (S[4*i+2] + s2);
                S[4*i+3] = egl[kb + 4*i+3] * (S[4*i+3] + s3);
            }
        }

        // ---- G: r = f @ Wr (packed .z/.w) ; voc *= silu(r) ----
        {
            const int t0 = th * 16;
            float ar[16];
            #pragma unroll
            for (int t = 0; t < 16; ++t) ar[t] = 0.0f;
            for (int cc = 0; cc < 64; ++cc) {
                float4 w = pWvr[cc * 256 + d];
                float col[17];
                #pragma unroll
                for (int i = 0; i < 4; ++i) {
                    float4 c4 = *(const float4*)&cur[cc][t0 + 4 * i];
                    col[4*i] = c4.x; col[4*i+1] = c4.y; col[4*i+2] = c4.z; col[4*i+3] = c4.w;
                }
                col[16] = cur[cc][t0 + 16];
                #pragma unroll
                for (int t = 0; t < 16; ++t) ar[t] += col[t] * w.z + col[t+1] * w.w;
            }
            #pragma unroll
            for (int t = 0; t < 16; ++t) {
                const float r = ar[t];
                voc[t0 + t][d] *= r / (1.0f + __expf(-r));
            }
        }
        __syncthreads();

        // ---- H: gdec = oc @ Wo ; thread = (4 cols, 2 rows), WoT float4 over j ----
        {
            const int cg = tid & 31;         // cols cg*4 .. cg*4+3
            const int rg = tid >> 5;         // rows rg*2, rg*2+1
            float accA[4] = {0,0,0,0}, accB[4] = {0,0,0,0};
            for (int jb = 0; jb < 64; ++jb) {
                float4 w0 = WoT4[(cg*4+0)*64 + jb];
                float4 w1 = WoT4[(cg*4+1)*64 + jb];
                float4 w2 = WoT4[(cg*4+2)*64 + jb];
                float4 w3 = WoT4[(cg*4+3)*64 + jb];
                float4 oa = *(const float4*)&voc[rg*2    ][4*jb];
                float4 ob = *(const float4*)&voc[rg*2 + 1][4*jb];
                accA[0] += oa.x*w0.x + oa.y*w0.y + oa.z*w0.z + oa.w*w0.w;
                accA[1] += oa.x*w1.x + oa.y*w1.y + oa.z*w1.z + oa.w*w1.w;
                accA[2] += oa.x*w2.x + oa.y*w2.y + oa.z*w2.z + oa.w*w2.w;
                accA[3] += oa.x*w3.x + oa.y*w3.y + oa.z*w3.z + oa.w*w3.w;
                accB[0] += ob.x*w0.x + ob.y*w0.y + ob.z*w0.z + ob.w*w0.w;
                accB[1] += ob.x*w1.x + ob.y*w1.y + ob.z*w1.z + ob.w*w1.w;
                accB[2] += ob.x*w2.x + ob.y*w2.y + ob.z*w2.z + ob.w*w2.w;
                accB[3] += ob.x*w3.x + ob.y*w3.y + ob.z*w3.z + ob.w*w3.w;
            }
            #pragma unroll
            for (int c = 0; c < 4; ++c) {
                gdec[(rg*2    ) * 132 + cg*4 + c] = accA[c];
                gdec[(rg*2 + 1) * 132 + cg*4 + c] = accB[c];
            }
        }
        __syncthreads();

        // ---- I: deconv1d (K=2) + bias + residual (from sxr) + store ----
        {
            const int o  = lane;
            const int pg = wv;               // 0..7 -> rows pg*4..+3
            const float2* ctw2 = (const float2*)ctw;
            float acc4[4] = {0,0,0,0};
            for (int c4 = 0; c4 < 128; c4 += 4) {
                float2 w0 = ctw2[(c4+0)*64 + o];
                float2 w1 = ctw2[(c4+1)*64 + o];
                float2 w2 = ctw2[(c4+2)*64 + o];
                float2 w3 = ctw2[(c4+3)*64 + o];
                float4 r[5];
                r[0] = (pg == 0) ? *(const float4*)&gprevs[c4]
                                 : *(const float4*)&gdec[(pg*4 - 1) * 132 + c4];
                #pragma unroll
                for (int j = 0; j < 4; ++j)
                    r[j+1] = *(const float4*)&gdec[(pg*4 + j) * 132 + c4];
                #pragma unroll
                for (int i = 0; i < 4; ++i) {
                    acc4[i] += r[i+1].x*w0.x + r[i].x*w0.y
                             + r[i+1].y*w1.x + r[i].y*w1.y
                             + r[i+1].z*w2.x + r[i].z*w2.y
                             + r[i+1].w*w3.x + r[i].w*w3.y;
                }
            }
            #pragma unroll
            for (int i = 0; i < 4; ++i) {
                const int tl = pg * 4 + i;
                const int oi = cbase + o * 32768 + (l0 + tl) * PSTRIDE;
                out[oi] = acc4[i] + bias + sxr[o][tl];
            }
        }
        __syncthreads();
        if (tid < 128) gprevs[tid] = gdec[31 * 132 + tid];
    }
}

extern "C" void kernel_launch(void* const* d_in, const int* in_sizes, int n_in,
                              void* d_out, int out_size, void* d_ws, size_t ws_size,
                              hipStream_t stream)
{
    const float* x = (const float*)d_in[0];
    float* y  = (float*)d_ws;               // intra output: 4*64*256*128 fp32
    float* pk = (float*)d_ws + 8388608;     // packed weights, 2 passes x 167936 floats
    float* z  = (float*)d_out;

    pack_weights<<<dim3(336), dim3(256), 0, stream>>>(
        (const float*)d_in[4],  (const float*)d_in[5],  (const float*)d_in[6],
        (const float*)d_in[9],  (const float*)d_in[7],  (const float*)d_in[11],
        (const float*)d_in[16], (const float*)d_in[17], (const float*)d_in[18],
        (const float*)d_in[21], (const float*)d_in[19], (const float*)d_in[23],
        pk);

    gla_pass<128, 1><<<dim3(1024), dim3(512), 0, stream>>>(
        x, y,
        (const float*)d_in[2],  (const float*)d_in[3],
        (const float4*)pk, (const float4*)(pk + 65536), (const float2*)(pk + 131072),
        (const float4*)(pk + 135168),
        (const float*)d_in[8],
        (const float*)d_in[10],
        (const float*)d_in[12], (const float*)d_in[13]);

    gla_pass<256, 128><<<dim3(512), dim3(512), 0, stream>>>(
        y, z,
        (const float*)d_in[14], (const float*)d_in[15],
        (const float4*)(pk + 167936), (const float4*)(pk + 167936 + 65536),
        (const float2*)(pk + 167936 + 131072),
        (const float4*)(pk + 167936 + 135168),
        (const float*)d_in[20],
        (const float*)d_in[22],
        (const float*)d_in[24], (const float*)d_in[25]);
}

// Round 8
// 7398.753 us; speedup vs baseline: 3.2755x; 1.0085x over previous
//
#include <hip/hip_runtime.h>

#define EPS 1e-5f

typedef _Float16 half_t;
typedef _Float16 h2_t __attribute__((ext_vector_type(2)));
union U16 { uint4 u; h2_t h[4]; };

__device__ __forceinline__ float logsig(float z) {
    return fminf(z, 0.0f) - log1pf(__expf(-fabsf(z)));
}

__device__ __forceinline__ float hdot2(h2_t a, h2_t b, float c) {
#if defined(__has_builtin)
#if __has_builtin(__builtin_amdgcn_fdot2)
    return __builtin_amdgcn_fdot2(a, b, c, false);
#else
    return c + (float)a[0] * (float)b[0] + (float)a[1] * (float)b[1];
#endif
#else
    return c + (float)a[0] * (float)b[0] + (float)a[1] * (float)b[1];
#endif
}

// One block = one sequence. 512 threads = 8 waves. R3 phase structure.
// R8: LDS diet 148KB -> ~80KB so TWO workgroups co-reside per CU (16 waves,
// 4/EU) -- the kernel is latency-bound (VALUBusy 34%, both passes equal dur
// despite opposite memory patterns), and 128-VGPR x 16 waves fits the RF.
// Diet: qf/kf/voc stored fp16 (dot2-f32 accumulate; S/Ats/o-accum/gates/LN/
// gdec/deconv all fp32), sxr dropped (resid re-read from global), single slab
// buffer (prefetch regs written back after G), fw1t/Ats/gdec share `uni`.
// Empirical RA law (R0/R1/R2/R6): VGPR cap pinned at 128 for <=512-thr blocks;
// attributes ignored. All designs must fit 128 regs.
template<int SLEN, int PSTRIDE>
__global__ __launch_bounds__(512)
void gla_pass(const float* __restrict__ src, float* __restrict__ out,
              const float* __restrict__ gamma, const float* __restrict__ beta,
              const float* __restrict__ Wq, const float* __restrict__ Wk,
              const float* __restrict__ Wv, const float* __restrict__ Wg1,
              const float* __restrict__ Wg2, const float* __restrict__ Wr,
              const float* __restrict__ gn, const float* __restrict__ Wo,
              const float* __restrict__ ctw, const float* __restrict__ ctb)
{
    constexpr int NC = SLEN / 32;
    constexpr int L  = SLEN - 1;

    __shared__ __align__(16) float  sx[64][36];    // slab (33 cols used)
    __shared__ __align__(16) half_t qsh[32][256];  // q*Dk^-0.5*exp(gc)   fp16
    __shared__ __align__(16) half_t ksh[32][256];  // k*exp(-gc)          fp16
    __shared__ __align__(16) half_t vsh[32][256];  // v -> oe1 -> o -> oc fp16
    __shared__ __align__(16) float  uni[4608];     // fw1t | Ats | gdec (fp32)
    __shared__ __align__(16) float  gprevs[128];
    __shared__ float egl[256];
    __shared__ float sgam[64], sbet[64];
    __shared__ float smu[33], sinv[33];
    __shared__ float gcarry[256];

    float* const fw1t = uni;          // m*36 + t          (p1 -> p2)
    float* const Ats  = uni;          // h*1152 + t*36 + s (F1 -> F2b)
    float* const gdec = uni;          // row*132 + c       (H -> I)

    const int tid  = threadIdx.x;
    const int lane = tid & 63;
    const int wv   = tid >> 6;        // 0..7
    const int h    = wv & 3;          // head
    const int kh   = wv >> 2;         // k-half
    const int d    = tid & 255;
    const int th   = (tid >> 8) & 1;  // t-half; th == kh
    const int n    = blockIdx.x;

    int b, fixedoff;
    if constexpr (PSTRIDE == 1) { b = n >> 8; fixedoff = (n & 255) * 128; }
    else                        { b = n >> 7; fixedoff = (n & 127); }
    const int cbase = (b * 64) * 32768 + fixedoff;

    if (tid < 64)  { sgam[tid] = gamma[tid]; sbet[tid] = beta[tid]; }
    if (tid < 128) gprevs[tid] = 0.0f;

    float S[32];
    #pragma unroll
    for (int k = 0; k < 32; ++k) S[k] = 0.0f;

    const float gnv  = gn[h * 64 + lane];
    const float bias = ctb[lane];

    // ---- prologue: chunk-0 slab ----
    #pragma unroll
    for (int k = 0; k < 5; ++k) {
        int idx = tid + k * 512;
        if (idx < 64 * 33) {
            int cc = idx / 33, i = idx - cc * 33;
            sx[cc][i] = src[cbase + cc * 32768 + i * PSTRIDE];
        }
    }

    for (int ch = 0; ch < NC; ++ch) {
        const int l0 = ch * 32;
        __syncthreads();              // sx(ch) raw ready

        // ---- A': next-chunk slab -> regs (written back after G) ----
        float pre[5];
        const bool pf = (ch + 1 < NC);
        if (pf) {
            const int l0n = l0 + 32;
            #pragma unroll
            for (int k = 0; k < 5; ++k) {
                int idx = tid + k * 512;
                if (idx < 64 * 33) {
                    int cc = idx / 33, i = idx - cc * 33;
                    int p  = l0n + i; if (p > SLEN - 1) p = SLEN - 1;
                    pre[k] = src[cbase + cc * 32768 + p * PSTRIDE];
                }
            }
        }

        // ---- B1: LN stats, wave-parallel ----
        for (int col = wv; col < 33; col += 8) {
            float x = sx[lane][col];
            float s1 = x, s2 = x * x;
            #pragma unroll
            for (int off = 32; off > 0; off >>= 1) {
                s1 += __shfl_xor(s1, off, 64);
                s2 += __shfl_xor(s2, off, 64);
            }
            if (lane == 0) {
                float mu  = s1 * (1.0f / 64.0f);
                float var = s2 * (1.0f / 64.0f) - mu * mu;
                smu[col]  = mu;
                sinv[col] = rsqrtf(fmaxf(var, 0.0f) + EPS);
            }
        }
        __syncthreads();

        // ---- B2: normalize in place ----
        #pragma unroll
        for (int k = 0; k < 5; ++k) {
            int idx = tid + k * 512;
            if (idx < 64 * 33) {
                int cc = idx / 33, i = idx - cc * 33;
                sx[cc][i] = (sx[cc][i] - smu[i]) * sinv[i] * sgam[cc] + sbet[cc];
            }
        }
        __syncthreads();

        // ---- p1: fw1t[m][t] ----
        {
            const int m = tid & 31, tg2 = tid >> 5;
            float a0 = 0.0f, a1 = 0.0f;
            for (int cc = 0; cc < 64; ++cc) {
                const float w0 = Wg1[(2*cc)*32 + m], w1 = Wg1[(2*cc+1)*32 + m];
                a0 += sx[cc][tg2]      * w0 + sx[cc][tg2 + 1]  * w1;
                a1 += sx[cc][tg2 + 16] * w0 + sx[cc][tg2 + 17] * w1;
            }
            fw1t[m * 36 + tg2] = a0; fw1t[m * 36 + tg2 + 16] = a1;
        }
        __syncthreads();

        // ---- p2: gate log-cumsum with carry -> rn[16], egl ----
        float rn[16];
        {
            const int t0 = th * 16;
            float acc2[16];
            #pragma unroll
            for (int t = 0; t < 16; ++t) acc2[t] = 0.0f;
            for (int mm = 0; mm < 32; ++mm) {
                const float w = Wg2[mm * 256 + d];
                #pragma unroll
                for (int i = 0; i < 4; ++i) {
                    float4 f4 = *(const float4*)&fw1t[mm * 36 + t0 + 4 * i];
                    acc2[4*i+0] += f4.x * w; acc2[4*i+1] += f4.y * w;
                    acc2[4*i+2] += f4.z * w; acc2[4*i+3] += f4.w * w;
                }
            }
            float r = 0.0f;
            #pragma unroll
            for (int t = 0; t < 16; ++t) {
                if ((l0 + t0 + t) < L) r += logsig(acc2[t]) * (1.0f / 32.0f);
                acc2[t] = r;
            }
            if (th == 0) gcarry[d] = r;
            __syncthreads();
            const float c = (th == 0) ? 0.0f : gcarry[d];
            #pragma unroll
            for (int t = 0; t < 16; ++t) rn[t] = c + acc2[t];
            if (th == 1) egl[d] = __expf(rn[15]);
        }

        // ---- C1: q,k fused projection -> fp16 stores ----
        {
            const int t0 = th * 16;
            float aq[16], ak[16];
            #pragma unroll
            for (int t = 0; t < 16; ++t) { aq[t] = 0.0f; ak[t] = 0.0f; }
            for (int cc = 0; cc < 64; ++cc) {
                float col[17];
                #pragma unroll
                for (int i = 0; i < 4; ++i) {
                    float4 c4 = *(const float4*)&sx[cc][t0 + 4 * i];
                    col[4*i] = c4.x; col[4*i+1] = c4.y; col[4*i+2] = c4.z; col[4*i+3] = c4.w;
                }
                col[16] = sx[cc][t0 + 16];
                const float wq0 = Wq[(2*cc)*256 + d], wq1 = Wq[(2*cc+1)*256 + d];
                const float wk0 = Wk[(2*cc)*256 + d], wk1 = Wk[(2*cc+1)*256 + d];
                #pragma unroll
                for (int t = 0; t < 16; ++t) {
                    aq[t] += col[t] * wq0 + col[t+1] * wq1;
                    ak[t] += col[t] * wk0 + col[t+1] * wk1;
                }
            }
            #pragma unroll
            for (int t = 0; t < 16; ++t) {
                bool valid = (l0 + t0 + t) < L;
                qsh[t0 + t][d] = (half_t)(valid ? aq[t] * 0.125f * __expf(rn[t]) : 0.0f);
                ksh[t0 + t][d] = (half_t)(valid ? ak[t] * __expf(-rn[t]) : 0.0f);
            }
        }
        // ---- C2: v projection -> fp16 store ----
        {
            const int t0 = th * 16;
            float av[16];
            #pragma unroll
            for (int t = 0; t < 16; ++t) av[t] = 0.0f;
            for (int cc = 0; cc < 64; ++cc) {
                float col[17];
                #pragma unroll
                for (int i = 0; i < 4; ++i) {
                    float4 c4 = *(const float4*)&sx[cc][t0 + 4 * i];
                    col[4*i] = c4.x; col[4*i+1] = c4.y; col[4*i+2] = c4.z; col[4*i+3] = c4.w;
                }
                col[16] = sx[cc][t0 + 16];
                const float wv0 = Wv[(2*cc)*256 + d], wv1 = Wv[(2*cc+1)*256 + d];
                #pragma unroll
                for (int t = 0; t < 16; ++t) av[t] += col[t] * wv0 + col[t+1] * wv1;
            }
            #pragma unroll
            for (int t = 0; t < 16; ++t)
                vsh[t0 + t][d] = (half_t)(((l0 + t0 + t) < L) ? av[t] : 0.0f);
        }
        __syncthreads();

        // ---- F: attention; 2 waves per head ----
        const int base = h * 64;
        float vcol[32];
        #pragma unroll
        for (int t = 0; t < 32; ++t) vcol[t] = (float)vsh[t][base + lane];

        // F1: triangular scores (fp16 dot2, fp32 accum) -> Ats fp32
        for (int pi = lane + 64 * kh; pi < 528; pi += 128) {
            float fpi = (float)pi;
            int t = (int)((sqrtf(8.0f * fpi + 1.0f) - 1.0f) * 0.5f);
            if (((t + 1) * (t + 2)) / 2 <= pi) ++t;
            if ((t * (t + 1)) / 2 > pi) --t;
            int s = pi - (t * (t + 1)) / 2;
            const uint4* q16 = (const uint4*)&qsh[t][base];
            const uint4* k16 = (const uint4*)&ksh[s][base];
            float a = 0.0f;
            #pragma unroll
            for (int ii = 0; ii < 8; ++ii) {
                int i = (ii + lane) & 7;
                U16 qa, ka; qa.u = q16[i]; ka.u = k16[i];
                #pragma unroll
                for (int j = 0; j < 4; ++j) a = hdot2(qa.h[j], ka.h[j], a);
            }
            Ats[h * 1152 + t * 36 + s] = a;
        }
        __syncthreads();   // A: Ats ready; vcol snapped

        // F2a: kh1 writes oe1 = q@S(rows 32..63) into vsh (fp16)
        if (kh == 1) {
            #pragma unroll
            for (int t = 0; t < 32; ++t) {
                const uint4* qp = (const uint4*)&qsh[t][base + 32];
                float oe = 0.0f;
                #pragma unroll
                for (int i = 0; i < 4; ++i) {
                    U16 u; u.u = qp[i];
                    #pragma unroll
                    for (int j = 0; j < 4; ++j) {
                        oe += (float)u.h[j][0] * S[i*8 + 2*j]
                            + (float)u.h[j][1] * S[i*8 + 2*j + 1];
                    }
                }
                vsh[t][base + lane] = (half_t)oe;
            }
        }
        __syncthreads();   // B: oe1 partials in vsh

        if (kh == 0) {
            // F2b: o = oe0 + oe1 + o_intra, RMS-norm -> vsh (fp16)
            #pragma unroll
            for (int t = 0; t < 32; ++t) {
                float ot = (float)vsh[t][base + lane];
                const uint4* qp = (const uint4*)&qsh[t][base];
                #pragma unroll
                for (int i = 0; i < 4; ++i) {
                    U16 u; u.u = qp[i];
                    #pragma unroll
                    for (int j = 0; j < 4; ++j) {
                        ot += (float)u.h[j][0] * S[i*8 + 2*j]
                            + (float)u.h[j][1] * S[i*8 + 2*j + 1];
                    }
                }
                const float* arow = &Ats[h * 1152 + t * 36];
                #pragma unroll
                for (int s4 = 0; s4 + 4 <= t + 1; s4 += 4) {
                    float4 a4 = *(const float4*)&arow[s4];
                    ot += a4.x*vcol[s4] + a4.y*vcol[s4+1] + a4.z*vcol[s4+2] + a4.w*vcol[s4+3];
                }
                #pragma unroll
                for (int s = (t + 1) & ~3; s <= t; ++s) ot += arow[s] * vcol[s];
                float ss = ot * ot;
                #pragma unroll
                for (int off = 32; off > 0; off >>= 1) ss += __shfl_xor(ss, off, 64);
                vsh[t][base + lane] = (half_t)(ot * rsqrtf(ss * (1.0f / 64.0f) + EPS) * gnv);
            }
        } else {
            // kh1: F4 state update rows 32..63
            const int kb = base + 32;
            #pragma unroll
            for (int i = 0; i < 4; ++i) {
                float s8[8] = {0,0,0,0,0,0,0,0};
                #pragma unroll
                for (int t = 0; t < 32; ++t) {
                    U16 u; u.u = *(const uint4*)&ksh[t][kb + 8*i];
                    const float vt = vcol[t];
                    #pragma unroll
                    for (int j = 0; j < 4; ++j) {
                        s8[2*j]   += (float)u.h[j][0] * vt;
                        s8[2*j+1] += (float)u.h[j][1] * vt;
                    }
                }
                #pragma unroll
                for (int j = 0; j < 8; ++j)
                    S[8*i+j] = egl[kb + 8*i + j] * (S[8*i+j] + s8[j]);
            }
        }
        __syncthreads();   // C: final o in vsh

        if (kh == 0) {
            // F4 state update rows 0..31
            const int kb = base;
            #pragma unroll
            for (int i = 0; i < 4; ++i) {
                float s8[8] = {0,0,0,0,0,0,0,0};
                #pragma unroll
                for (int t = 0; t < 32; ++t) {
                    U16 u; u.u = *(const uint4*)&ksh[t][kb + 8*i];
                    const float vt = vcol[t];
                    #pragma unroll
                    for (int j = 0; j < 4; ++j) {
                        s8[2*j]   += (float)u.h[j][0] * vt;
                        s8[2*j+1] += (float)u.h[j][1] * vt;
                    }
                }
                #pragma unroll
                for (int j = 0; j < 8; ++j)
                    S[8*i+j] = egl[kb + 8*i + j] * (S[8*i+j] + s8[j]);
            }
        }

        // ---- G: r = f @ Wr ; vsh *= silu(r) ----
        {
            const int t0 = th * 16;
            float ar[16];
            #pragma unroll
            for (int t = 0; t < 16; ++t) ar[t] = 0.0f;
            for (int cc = 0; cc < 64; ++cc) {
                float col[17];
                #pragma unroll
                for (int i = 0; i < 4; ++i) {
                    float4 c4 = *(const float4*)&sx[cc][t0 + 4 * i];
                    col[4*i] = c4.x; col[4*i+1] = c4.y; col[4*i+2] = c4.z; col[4*i+3] = c4.w;
                }
                col[16] = sx[cc][t0 + 16];
                const float w0 = Wr[(2*cc)*256 + d], w1 = Wr[(2*cc+1)*256 + d];
                #pragma unroll
                for (int t = 0; t < 16; ++t) ar[t] += col[t] * w0 + col[t+1] * w1;
            }
            #pragma unroll
            for (int t = 0; t < 16; ++t) {
                const float r  = ar[t];
                const float ov = (float)vsh[t0 + t][d];
                vsh[t0 + t][d] = (half_t)(ov * r / (1.0f + __expf(-r)));
            }
        }
        __syncthreads();

        // ---- A'': write prefetched slab (sx dead after G) ----
        if (pf) {
            #pragma unroll
            for (int k = 0; k < 5; ++k) {
                int idx = tid + k * 512;
                if (idx < 64 * 33) {
                    int cc = idx / 33, i = idx - cc * 33;
                    sx[cc][i] = pre[k];
                }
            }
        }
        // ---- residual preload for I (early issue; hides under H) ----
        float resid[4];
        #pragma unroll
        for (int i = 0; i < 4; ++i)
            resid[i] = src[cbase + lane * 32768 + (l0 + wv * 4 + i) * PSTRIDE];

        // ---- H: gdec = oc @ Wo (oc fp16, fp32 accum) ----
        {
            const int m2  = tid & 63;
            const int tg4 = tid >> 6;        // rows tg4*4..+3
            float accA[4] = {0,0,0,0}, accB[4] = {0,0,0,0};
            for (int jb = 0; jb < 32; ++jb) {   // 8 j's per step
                float wA[8], wB[8];
                #pragma unroll
                for (int u2 = 0; u2 < 8; ++u2) {
                    wA[u2] = Wo[(8*jb + u2)*128 + m2];
                    wB[u2] = Wo[(8*jb + u2)*128 + m2 + 64];
                }
                #pragma unroll
                for (int i = 0; i < 4; ++i) {
                    U16 u; u.u = *(const uint4*)&vsh[tg4 * 4 + i][8 * jb];
                    #pragma unroll
                    for (int j = 0; j < 4; ++j) {
                        float o0 = (float)u.h[j][0], o1 = (float)u.h[j][1];
                        accA[i] += o0 * wA[2*j] + o1 * wA[2*j+1];
                        accB[i] += o0 * wB[2*j] + o1 * wB[2*j+1];
                    }
                }
            }
            #pragma unroll
            for (int i = 0; i < 4; ++i) {
                gdec[(tg4 * 4 + i) * 132 + m2]      = accA[i];
                gdec[(tg4 * 4 + i) * 132 + m2 + 64] = accB[i];
            }
        }
        __syncthreads();

        // ---- I: deconv1d (K=2) + bias + residual + store ----
        {
            const int o  = lane;
            const int pg = wv;               // rows pg*4..+3
            const float2* ctw2 = (const float2*)ctw;
            float acc4[4] = {0,0,0,0};
            for (int c4 = 0; c4 < 128; c4 += 4) {
                float2 w0 = ctw2[(c4+0)*64 + o];
                float2 w1 = ctw2[(c4+1)*64 + o];
                float2 w2 = ctw2[(c4+2)*64 + o];
                float2 w3 = ctw2[(c4+3)*64 + o];
                float4 r[5];
                r[0] = (pg == 0) ? *(const float4*)&gprevs[c4]
                                 : *(const float4*)&gdec[(pg*4 - 1) * 132 + c4];
                #pragma unroll
                for (int j = 0; j < 4; ++j)
                    r[j+1] = *(const float4*)&gdec[(pg*4 + j) * 132 + c4];
                #pragma unroll
                for (int i = 0; i < 4; ++i) {
                    acc4[i] += r[i+1].x*w0.x + r[i].x*w0.y
                             + r[i+1].y*w1.x + r[i].y*w1.y
                             + r[i+1].z*w2.x + r[i].z*w2.y
                             + r[i+1].w*w3.x + r[i].w*w3.y;
                }
            }
            #pragma unroll
            for (int i = 0; i < 4; ++i) {
                const int tl = pg * 4 + i;
                const int oi = cbase + o * 32768 + (l0 + tl) * PSTRIDE;
                out[oi] = acc4[i] + bias + resid[i];
            }
        }
        __syncthreads();
        if (tid < 128) gprevs[tid] = gdec[31 * 132 + tid];
    }
}

extern "C" void kernel_launch(void* const* d_in, const int* in_sizes, int n_in,
                              void* d_out, int out_size, void* d_ws, size_t ws_size,
                              hipStream_t stream)
{
    const float* x = (const float*)d_in[0];
    float* y = (float*)d_ws;     // intra output: 4*64*256*128 fp32
    float* z = (float*)d_out;

    gla_pass<128, 1><<<dim3(1024), dim3(512), 0, stream>>>(
        x, y,
        (const float*)d_in[2],  (const float*)d_in[3],  (const float*)d_in[4],
        (const float*)d_in[5],  (const float*)d_in[6],  (const float*)d_in[7],
        (const float*)d_in[8],  (const float*)d_in[9],  (const float*)d_in[10],
        (const float*)d_in[11], (const float*)d_in[12], (const float*)d_in[13]);

    gla_pass<256, 128><<<dim3(512), dim3(512), 0, stream>>>(
        y, z,
        (const float*)d_in[14], (const float*)d_in[15], (const float*)d_in[16],
        (const float*)d_in[17], (const float*)d_in[18], (const float*)d_in[19],
        (const float*)d_in[20], (const float*)d_in[21], (const float*)d_in[22],
        (const float*)d_in[23], (const float*)d_in[24], (const float*)d_in[25]);
}

// Round 9
// 6397.021 us; speedup vs baseline: 3.7884x; 1.1566x over previous
//
#include <hip/hip_runtime.h>

#define EPS 1e-5f

typedef _Float16 half_t;
typedef _Float16 h2_t __attribute__((ext_vector_type(2)));
union U16 { uint4 u; h2_t h[4]; };

__device__ __forceinline__ float logsig(float z) {
    return fminf(z, 0.0f) - log1pf(__expf(-fabsf(z)));
}

__device__ __forceinline__ float hdot2(h2_t a, h2_t b, float c) {
#if defined(__has_builtin)
#if __has_builtin(__builtin_amdgcn_fdot2)
    return __builtin_amdgcn_fdot2(a, b, c, false);
#else
    return c + (float)a[0] * (float)b[0] + (float)a[1] * (float)b[1];
#endif
#else
    return c + (float)a[0] * (float)b[0] + (float)a[1] * (float)b[1];
#endif
}

// One block = one sequence. 512 threads = 8 waves. R3 phase structure.
// R9: finish R8's dual-residency plan. R8 hit 80384B LDS -> 2nd workgroup
// still didn't fit (occupancy stayed 24.5%; R6 proved 77824B DOES co-schedule).
// Shave 4KB by (a) triangular-packed Ats (528 floats/head, indexed by the pi
// F1 already computes), (b) ALL transients overlaid in one 4224-float region:
//   smu/sinv (B)  | fw1t[0,1152)+gcarry[1152,1408) (gate) |
//   Ats[0,2112)+egl[2112,2368) (F) | gdec[0,4224) (H->I)
// Lifetimes disjoint vs the barrier structure. Total 76288B <= 77824B proven
// threshold -> two 512-thr workgroups/CU (16 waves, 4/EU; 128 VGPR x 4 waves
// = full 512-reg SIMD file).
// Empirical RA law (R0/R1/R2/R6): VGPR cap pinned at 128; attrs ignored.
template<int SLEN, int PSTRIDE>
__global__ __launch_bounds__(512)
void gla_pass(const float* __restrict__ src, float* __restrict__ out,
              const float* __restrict__ gamma, const float* __restrict__ beta,
              const float* __restrict__ Wq, const float* __restrict__ Wk,
              const float* __restrict__ Wv, const float* __restrict__ Wg1,
              const float* __restrict__ Wg2, const float* __restrict__ Wr,
              const float* __restrict__ gn, const float* __restrict__ Wo,
              const float* __restrict__ ctw, const float* __restrict__ ctb)
{
    constexpr int NC = SLEN / 32;
    constexpr int L  = SLEN - 1;

    __shared__ __align__(16) float  sx[64][36];    // slab (33 cols used)
    __shared__ __align__(16) half_t qsh[32][256];  // q*Dk^-0.5*exp(gc)   fp16
    __shared__ __align__(16) half_t ksh[32][256];  // k*exp(-gc)          fp16
    __shared__ __align__(16) half_t vsh[32][256];  // v -> oe1 -> o -> oc fp16
    __shared__ __align__(16) float  uni[4224];     // overlaid transients (fp32)
    __shared__ __align__(16) float  gprevs[128];
    __shared__ float sgam[64], sbet[64];

    float* const smu    = uni;          // 33        (B1 -> B2)
    float* const sinv   = uni + 40;     // 33        (B1 -> B2)
    float* const fw1t   = uni;          // m*36+t    (p1 -> p2)
    float* const gcarry = uni + 1152;   // 256       (p2)
    float* const Ats    = uni;          // h*528+pi  (F1 -> F2b)
    float* const egl    = uni + 2112;   // 256       (p2 -> F4)
    float* const gdec   = uni;          // row*132+c (H -> I)

    const int tid  = threadIdx.x;
    const int lane = tid & 63;
    const int wv   = tid >> 6;        // 0..7
    const int h    = wv & 3;          // head
    const int kh   = wv >> 2;         // k-half
    const int d    = tid & 255;
    const int th   = (tid >> 8) & 1;  // t-half; th == kh
    const int n    = blockIdx.x;

    int b, fixedoff;
    if constexpr (PSTRIDE == 1) { b = n >> 8; fixedoff = (n & 255) * 128; }
    else                        { b = n >> 7; fixedoff = (n & 127); }
    const int cbase = (b * 64) * 32768 + fixedoff;

    if (tid < 64)  { sgam[tid] = gamma[tid]; sbet[tid] = beta[tid]; }
    if (tid < 128) gprevs[tid] = 0.0f;

    float S[32];
    #pragma unroll
    for (int k = 0; k < 32; ++k) S[k] = 0.0f;

    const float gnv  = gn[h * 64 + lane];
    const float bias = ctb[lane];

    // ---- prologue: chunk-0 slab ----
    #pragma unroll
    for (int k = 0; k < 5; ++k) {
        int idx = tid + k * 512;
        if (idx < 64 * 33) {
            int cc = idx / 33, i = idx - cc * 33;
            sx[cc][i] = src[cbase + cc * 32768 + i * PSTRIDE];
        }
    }

    for (int ch = 0; ch < NC; ++ch) {
        const int l0 = ch * 32;
        __syncthreads();              // sx(ch) raw ready

        // ---- A': next-chunk slab -> regs (written back after G) ----
        float pre[5];
        const bool pf = (ch + 1 < NC);
        if (pf) {
            const int l0n = l0 + 32;
            #pragma unroll
            for (int k = 0; k < 5; ++k) {
                int idx = tid + k * 512;
                if (idx < 64 * 33) {
                    int cc = idx / 33, i = idx - cc * 33;
                    int p  = l0n + i; if (p > SLEN - 1) p = SLEN - 1;
                    pre[k] = src[cbase + cc * 32768 + p * PSTRIDE];
                }
            }
        }

        // ---- B1: LN stats, wave-parallel ----
        for (int col = wv; col < 33; col += 8) {
            float x = sx[lane][col];
            float s1 = x, s2 = x * x;
            #pragma unroll
            for (int off = 32; off > 0; off >>= 1) {
                s1 += __shfl_xor(s1, off, 64);
                s2 += __shfl_xor(s2, off, 64);
            }
            if (lane == 0) {
                float mu  = s1 * (1.0f / 64.0f);
                float var = s2 * (1.0f / 64.0f) - mu * mu;
                smu[col]  = mu;
                sinv[col] = rsqrtf(fmaxf(var, 0.0f) + EPS);
            }
        }
        __syncthreads();

        // ---- B2: normalize in place ----
        #pragma unroll
        for (int k = 0; k < 5; ++k) {
            int idx = tid + k * 512;
            if (idx < 64 * 33) {
                int cc = idx / 33, i = idx - cc * 33;
                sx[cc][i] = (sx[cc][i] - smu[i]) * sinv[i] * sgam[cc] + sbet[cc];
            }
        }
        __syncthreads();

        // ---- p1: fw1t[m][t] (overwrites smu/sinv region; they are dead) ----
        {
            const int m = tid & 31, tg2 = tid >> 5;
            float a0 = 0.0f, a1 = 0.0f;
            for (int cc = 0; cc < 64; ++cc) {
                const float w0 = Wg1[(2*cc)*32 + m], w1 = Wg1[(2*cc+1)*32 + m];
                a0 += sx[cc][tg2]      * w0 + sx[cc][tg2 + 1]  * w1;
                a1 += sx[cc][tg2 + 16] * w0 + sx[cc][tg2 + 17] * w1;
            }
            fw1t[m * 36 + tg2] = a0; fw1t[m * 36 + tg2 + 16] = a1;
        }
        __syncthreads();

        // ---- p2: gate log-cumsum with carry -> rn[16], egl ----
        float rn[16];
        {
            const int t0 = th * 16;
            float acc2[16];
            #pragma unroll
            for (int t = 0; t < 16; ++t) acc2[t] = 0.0f;
            for (int mm = 0; mm < 32; ++mm) {
                const float w = Wg2[mm * 256 + d];
                #pragma unroll
                for (int i = 0; i < 4; ++i) {
                    float4 f4 = *(const float4*)&fw1t[mm * 36 + t0 + 4 * i];
                    acc2[4*i+0] += f4.x * w; acc2[4*i+1] += f4.y * w;
                    acc2[4*i+2] += f4.z * w; acc2[4*i+3] += f4.w * w;
                }
            }
            float r = 0.0f;
            #pragma unroll
            for (int t = 0; t < 16; ++t) {
                if ((l0 + t0 + t) < L) r += logsig(acc2[t]) * (1.0f / 32.0f);
                acc2[t] = r;
            }
            if (th == 0) gcarry[d] = r;
            __syncthreads();
            const float c = (th == 0) ? 0.0f : gcarry[d];
            #pragma unroll
            for (int t = 0; t < 16; ++t) rn[t] = c + acc2[t];
            if (th == 1) egl[d] = __expf(rn[15]);
        }

        // ---- C1: q,k fused projection -> fp16 stores ----
        {
            const int t0 = th * 16;
            float aq[16], ak[16];
            #pragma unroll
            for (int t = 0; t < 16; ++t) { aq[t] = 0.0f; ak[t] = 0.0f; }
            for (int cc = 0; cc < 64; ++cc) {
                float col[17];
                #pragma unroll
                for (int i = 0; i < 4; ++i) {
                    float4 c4 = *(const float4*)&sx[cc][t0 + 4 * i];
                    col[4*i] = c4.x; col[4*i+1] = c4.y; col[4*i+2] = c4.z; col[4*i+3] = c4.w;
                }
                col[16] = sx[cc][t0 + 16];
                const float wq0 = Wq[(2*cc)*256 + d], wq1 = Wq[(2*cc+1)*256 + d];
                const float wk0 = Wk[(2*cc)*256 + d], wk1 = Wk[(2*cc+1)*256 + d];
                #pragma unroll
                for (int t = 0; t < 16; ++t) {
                    aq[t] += col[t] * wq0 + col[t+1] * wq1;
                    ak[t] += col[t] * wk0 + col[t+1] * wk1;
                }
            }
            #pragma unroll
            for (int t = 0; t < 16; ++t) {
                bool valid = (l0 + t0 + t) < L;
                qsh[t0 + t][d] = (half_t)(valid ? aq[t] * 0.125f * __expf(rn[t]) : 0.0f);
                ksh[t0 + t][d] = (half_t)(valid ? ak[t] * __expf(-rn[t]) : 0.0f);
            }
        }
        // ---- C2: v projection -> fp16 store ----
        {
            const int t0 = th * 16;
            float av[16];
            #pragma unroll
            for (int t = 0; t < 16; ++t) av[t] = 0.0f;
            for (int cc = 0; cc < 64; ++cc) {
                float col[17];
                #pragma unroll
                for (int i = 0; i < 4; ++i) {
                    float4 c4 = *(const float4*)&sx[cc][t0 + 4 * i];
                    col[4*i] = c4.x; col[4*i+1] = c4.y; col[4*i+2] = c4.z; col[4*i+3] = c4.w;
                }
                col[16] = sx[cc][t0 + 16];
                const float wv0 = Wv[(2*cc)*256 + d], wv1 = Wv[(2*cc+1)*256 + d];
                #pragma unroll
                for (int t = 0; t < 16; ++t) av[t] += col[t] * wv0 + col[t+1] * wv1;
            }
            #pragma unroll
            for (int t = 0; t < 16; ++t)
                vsh[t0 + t][d] = (half_t)(((l0 + t0 + t) < L) ? av[t] : 0.0f);
        }
        __syncthreads();

        // ---- F: attention; 2 waves per head ----
        const int base = h * 64;
        float vcol[32];
        #pragma unroll
        for (int t = 0; t < 32; ++t) vcol[t] = (float)vsh[t][base + lane];

        // F1: triangular scores (fp16 dot2, fp32 accum) -> tri-packed Ats
        for (int pi = lane + 64 * kh; pi < 528; pi += 128) {
            float fpi = (float)pi;
            int t = (int)((sqrtf(8.0f * fpi + 1.0f) - 1.0f) * 0.5f);
            if (((t + 1) * (t + 2)) / 2 <= pi) ++t;
            if ((t * (t + 1)) / 2 > pi) --t;
            int s = pi - (t * (t + 1)) / 2;
            const uint4* q16 = (const uint4*)&qsh[t][base];
            const uint4* k16 = (const uint4*)&ksh[s][base];
            float a = 0.0f;
            #pragma unroll
            for (int ii = 0; ii < 8; ++ii) {
                int i = (ii + lane) & 7;
                U16 qa, ka; qa.u = q16[i]; ka.u = k16[i];
                #pragma unroll
                for (int j = 0; j < 4; ++j) a = hdot2(qa.h[j], ka.h[j], a);
            }
            Ats[h * 528 + pi] = a;
        }
        __syncthreads();   // A: Ats ready; vcol snapped

        // F2a: kh1 writes oe1 = q@S(rows 32..63) into vsh (fp16)
        if (kh == 1) {
            #pragma unroll
            for (int t = 0; t < 32; ++t) {
                const uint4* qp = (const uint4*)&qsh[t][base + 32];
                float oe = 0.0f;
                #pragma unroll
                for (int i = 0; i < 4; ++i) {
                    U16 u; u.u = qp[i];
                    #pragma unroll
                    for (int j = 0; j < 4; ++j) {
                        oe += (float)u.h[j][0] * S[i*8 + 2*j]
                            + (float)u.h[j][1] * S[i*8 + 2*j + 1];
                    }
                }
                vsh[t][base + lane] = (half_t)oe;
            }
        }
        __syncthreads();   // B: oe1 partials in vsh

        if (kh == 0) {
            // F2b: o = oe0 + oe1 + o_intra, RMS-norm -> vsh (fp16)
            #pragma unroll
            for (int t = 0; t < 32; ++t) {
                float ot = (float)vsh[t][base + lane];
                const uint4* qp = (const uint4*)&qsh[t][base];
                #pragma unroll
                for (int i = 0; i < 4; ++i) {
                    U16 u; u.u = qp[i];
                    #pragma unroll
                    for (int j = 0; j < 4; ++j) {
                        ot += (float)u.h[j][0] * S[i*8 + 2*j]
                            + (float)u.h[j][1] * S[i*8 + 2*j + 1];
                    }
                }
                const float* arow = &Ats[h * 528 + (t * (t + 1)) / 2];
                #pragma unroll
                for (int s = 0; s <= t; ++s) ot += arow[s] * vcol[s];
                float ss = ot * ot;
                #pragma unroll
                for (int off = 32; off > 0; off >>= 1) ss += __shfl_xor(ss, off, 64);
                vsh[t][base + lane] = (half_t)(ot * rsqrtf(ss * (1.0f / 64.0f) + EPS) * gnv);
            }
        } else {
            // kh1: F4 state update rows 32..63
            const int kb = base + 32;
            #pragma unroll
            for (int i = 0; i < 4; ++i) {
                float s8[8] = {0,0,0,0,0,0,0,0};
                #pragma unroll
                for (int t = 0; t < 32; ++t) {
                    U16 u; u.u = *(const uint4*)&ksh[t][kb + 8*i];
                    const float vt = vcol[t];
                    #pragma unroll
                    for (int j = 0; j < 4; ++j) {
                        s8[2*j]   += (float)u.h[j][0] * vt;
                        s8[2*j+1] += (float)u.h[j][1] * vt;
                    }
                }
                #pragma unroll
                for (int j = 0; j < 8; ++j)
                    S[8*i+j] = egl[kb + 8*i + j] * (S[8*i+j] + s8[j]);
            }
        }
        __syncthreads();   // C: final o in vsh

        if (kh == 0) {
            // F4 state update rows 0..31
            const int kb = base;
            #pragma unroll
            for (int i = 0; i < 4; ++i) {
                float s8[8] = {0,0,0,0,0,0,0,0};
                #pragma unroll
                for (int t = 0; t < 32; ++t) {
                    U16 u; u.u = *(const uint4*)&ksh[t][kb + 8*i];
                    const float vt = vcol[t];
                    #pragma unroll
                    for (int j = 0; j < 4; ++j) {
                        s8[2*j]   += (float)u.h[j][0] * vt;
                        s8[2*j+1] += (float)u.h[j][1] * vt;
                    }
                }
                #pragma unroll
                for (int j = 0; j < 8; ++j)
                    S[8*i+j] = egl[kb + 8*i + j] * (S[8*i+j] + s8[j]);
            }
        }

        // ---- G: r = f @ Wr ; vsh *= silu(r) ----
        {
            const int t0 = th * 16;
            float ar[16];
            #pragma unroll
            for (int t = 0; t < 16; ++t) ar[t] = 0.0f;
            for (int cc = 0; cc < 64; ++cc) {
                float col[17];
                #pragma unroll
                for (int i = 0; i < 4; ++i) {
                    float4 c4 = *(const float4*)&sx[cc][t0 + 4 * i];
                    col[4*i] = c4.x; col[4*i+1] = c4.y; col[4*i+2] = c4.z; col[4*i+3] = c4.w;
                }
                col[16] = sx[cc][t0 + 16];
                const float w0 = Wr[(2*cc)*256 + d], w1 = Wr[(2*cc+1)*256 + d];
                #pragma unroll
                for (int t = 0; t < 16; ++t) ar[t] += col[t] * w0 + col[t+1] * w1;
            }
            #pragma unroll
            for (int t = 0; t < 16; ++t) {
                const float r  = ar[t];
                const float ov = (float)vsh[t0 + t][d];
                vsh[t0 + t][d] = (half_t)(ov * r / (1.0f + __expf(-r)));
            }
        }
        __syncthreads();

        // ---- A'': write prefetched slab (sx dead after G) ----
        if (pf) {
            #pragma unroll
            for (int k = 0; k < 5; ++k) {
                int idx = tid + k * 512;
                if (idx < 64 * 33) {
                    int cc = idx / 33, i = idx - cc * 33;
                    sx[cc][i] = pre[k];
                }
            }
        }
        // ---- residual preload for I (early issue; hides under H) ----
        float resid[4];
        #pragma unroll
        for (int i = 0; i < 4; ++i)
            resid[i] = src[cbase + lane * 32768 + (l0 + wv * 4 + i) * PSTRIDE];

        // ---- H: gdec = oc @ Wo (oc fp16, fp32 accum) ----
        {
            const int m2  = tid & 63;
            const int tg4 = tid >> 6;        // rows tg4*4..+3
            float accA[4] = {0,0,0,0}, accB[4] = {0,0,0,0};
            for (int jb = 0; jb < 32; ++jb) {   // 8 j's per step
                float wA[8], wB[8];
                #pragma unroll
                for (int u2 = 0; u2 < 8; ++u2) {
                    wA[u2] = Wo[(8*jb + u2)*128 + m2];
                    wB[u2] = Wo[(8*jb + u2)*128 + m2 + 64];
                }
                #pragma unroll
                for (int i = 0; i < 4; ++i) {
                    U16 u; u.u = *(const uint4*)&vsh[tg4 * 4 + i][8 * jb];
                    #pragma unroll
                    for (int j = 0; j < 4; ++j) {
                        float o0 = (float)u.h[j][0], o1 = (float)u.h[j][1];
                        accA[i] += o0 * wA[2*j] + o1 * wA[2*j+1];
                        accB[i] += o0 * wB[2*j] + o1 * wB[2*j+1];
                    }
                }
            }
            #pragma unroll
            for (int i = 0; i < 4; ++i) {
                gdec[(tg4 * 4 + i) * 132 + m2]      = accA[i];
                gdec[(tg4 * 4 + i) * 132 + m2 + 64] = accB[i];
            }
        }
        __syncthreads();

        // ---- I: deconv1d (K=2) + bias + residual + store ----
        {
            const int o  = lane;
            const int pg = wv;               // rows pg*4..+3
            const float2* ctw2 = (const float2*)ctw;
            float acc4[4] = {0,0,0,0};
            for (int c4 = 0; c4 < 128; c4 += 4) {
                float2 w0 = ctw2[(c4+0)*64 + o];
                float2 w1 = ctw2[(c4+1)*64 + o];
                float2 w2 = ctw2[(c4+2)*64 + o];
                float2 w3 = ctw2[(c4+3)*64 + o];
                float4 r[5];
                r[0] = (pg == 0) ? *(const float4*)&gprevs[c4]
                                 : *(const float4*)&gdec[(pg*4 - 1) * 132 + c4];
                #pragma unroll
                for (int j = 0; j < 4; ++j)
                    r[j+1] = *(const float4*)&gdec[(pg*4 + j) * 132 + c4];
                #pragma unroll
                for (int i = 0; i < 4; ++i) {
                    acc4[i] += r[i+1].x*w0.x + r[i].x*w0.y
                             + r[i+1].y*w1.x + r[i].y*w1.y
                             + r[i+1].z*w2.x + r[i].z*w2.y
                             + r[i+1].w*w3.x + r[i].w*w3.y;
                }
            }
            #pragma unroll
            for (int i = 0; i < 4; ++i) {
                const int tl = pg * 4 + i;
                const int oi = cbase + o * 32768 + (l0 + tl) * PSTRIDE;
                out[oi] = acc4[i] + bias + resid[i];
            }
        }
        __syncthreads();
        if (tid < 128) gprevs[tid] = gdec[31 * 132 + tid];
    }
}

extern "C" void kernel_launch(void* const* d_in, const int* in_sizes, int n_in,
                              void* d_out, int out_size, void* d_ws, size_t ws_size,
                              hipStream_t stream)
{
    const float* x = (const float*)d_in[0];
    float* y = (float*)d_ws;     // intra output: 4*64*256*128 fp32
    float* z = (float*)d_out;

    gla_pass<128, 1><<<dim3(1024), dim3(512), 0, stream>>>(
        x, y,
        (const float*)d_in[2],  (const float*)d_in[3],  (const float*)d_in[4],
        (const float*)d_in[5],  (const float*)d_in[6],  (const float*)d_in[7],
        (const float*)d_in[8],  (const float*)d_in[9],  (const float*)d_in[10],
        (const float*)d_in[11], (const float*)d_in[12], (const float*)d_in[13]);

    gla_pass<256, 128><<<dim3(512), dim3(512), 0, stream>>>(
        y, z,
        (const float*)d_in[14], (const float*)d_in[15], (const float*)d_in[16],
        (const float*)d_in[17], (const float*)d_in[18], (const float*)d_in[19],
        (const float*)d_in[20], (const float*)d_in[21], (const float*)d_in[22],
        (const float*)d_in[23], (const float*)d_in[24], (const float*)d_in[25]);
}

// Round 10
// 6060.751 us; speedup vs baseline: 3.9986x; 1.0555x over previous
//
#include <hip/hip_runtime.h>

#define EPS 1e-5f

__device__ __forceinline__ float logsig(float z) {
    return fminf(z, 0.0f) - log1pf(__expf(-fabsf(z)));
}

// One block = one sequence. 512 threads = 8 waves.
// Head h = wave&3; k-half kh = wave>>2 (kh0 holds S rows 0..31, kh1 rows 32..63).
// PSTRIDE==1  : intra pass (seq over q, SLEN=128); PSTRIDE==128: inter pass (SLEN=256)
// HW facts established R0-R9:
//  - VGPR cap pinned at 128 for any block shape (attrs ignored).
//  - waves/CU x VGPR = 1024 (unified VGPR/AGPR mirror): at 128 regs the CU
//    holds exactly 8 waves NO MATTER the LDS -> dual-residency unreachable;
//    TLP capped at 2 waves/EU. fp16 LDS diet (R8/R9) = pure cost. Designs
//    must fit 128 regs and minimize exposed latency per wave.
// R3 (this base, 5909us): slab double-buffer + reg prefetch, wave-parallel LN,
// Ats/gdec overlay.
// R10: prefetch code-motion only. The compiler drains vmcnt(0) at EVERY
// barrier, so chunk-top issue stalled the whole block at the B1 barrier.
// Issue now happens right after the G barrier (latency hides under H, the
// longest phase), LDS write after the H barrier. Also frees pre[5] from the
// register-critical C phase.
template<int SLEN, int PSTRIDE>
__global__ __launch_bounds__(512)
__attribute__((amdgpu_waves_per_eu(2, 2)))
void gla_pass(const float* __restrict__ src, float* __restrict__ out,
              const float* __restrict__ gamma, const float* __restrict__ beta,
              const float* __restrict__ Wq, const float* __restrict__ Wk,
              const float* __restrict__ Wv, const float* __restrict__ Wg1,
              const float* __restrict__ Wg2, const float* __restrict__ Wr,
              const float* __restrict__ gn, const float* __restrict__ Wo,
              const float* __restrict__ ctw, const float* __restrict__ ctb)
{
    constexpr int NC = SLEN / 32;
    constexpr int L  = SLEN - 1;

    __shared__ __align__(16) float sxA[64][36];   // slab buffer A (33 cols used)
    __shared__ __align__(16) float sxB[64][36];   // slab buffer B
    __shared__ __align__(16) float sxr[64][32];   // raw slab (residual source)
    __shared__ __align__(16) float qf[32][256];   // q*Dk^-0.5 * exp(gc)
    __shared__ __align__(16) float kf[32][256];   // k * exp(-gc)
    __shared__ __align__(16) float voc[32][256];  // v -> oe1 partial -> o -> o*silu(r)
    __shared__ __align__(16) float uni[4608];     // Ats[4][32][36] OVERLAID with gdec[32][132]
    __shared__ __align__(16) float fw1t[32][36];  // (f @ Wg1)^T : fw1t[m][t]
    __shared__ __align__(16) float gprevs[128];   // deconv carry row
    __shared__ float egl[256];                    // exp(chunk-total gate)
    __shared__ float sgam[64], sbet[64];
    __shared__ float smu[33], sinv[33];
    __shared__ float gcarry[256];                 // gate cumsum carry (t=0..15 total)

    float* const Ats  = uni;          // h*1152 + t*36 + s      (live F1 -> F2b)
    float* const gdec = uni;          // row*132 + c            (live H -> I; Ats dead)

    const int tid  = threadIdx.x;
    const int lane = tid & 63;
    const int wv   = tid >> 6;        // 0..7
    const int h    = wv & 3;          // head
    const int kh   = wv >> 2;         // k-half
    const int d    = tid & 255;       // column for t-split stages
    const int th   = (tid >> 8) & 1;  // t-half (rows th*16 .. th*16+15); th == kh
    const int n    = blockIdx.x;

    int b, fixedoff;
    if constexpr (PSTRIDE == 1) { b = n >> 8; fixedoff = (n & 255) * 128; }
    else                        { b = n >> 7; fixedoff = (n & 127); }
    const int cbase = (b * 64) * 32768 + fixedoff;

    if (tid < 64)  { sgam[tid] = gamma[tid]; sbet[tid] = beta[tid]; }
    if (tid < 128) gprevs[tid] = 0.0f;

    float S[32];
    #pragma unroll
    for (int k = 0; k < 32; ++k) S[k] = 0.0f;

    const float gnv  = gn[h * 64 + lane];
    const float bias = ctb[lane];

    // ---- prologue: chunk-0 slab -> sxA (raw) ----
    #pragma unroll
    for (int k = 0; k < 5; ++k) {
        int idx = tid + k * 512;
        if (idx < 64 * 33) {
            int cc = idx / 33, i = idx - cc * 33;
            sxA[cc][i] = src[cbase + cc * 32768 + i * PSTRIDE];
        }
    }

    for (int ch = 0; ch < NC; ++ch) {
        const int l0 = ch * 32;
        float (* const cur)[36] = (ch & 1) ? sxB : sxA;
        float (* const nxt)[36] = (ch & 1) ? sxA : sxB;
        const bool pf = (ch + 1 < NC);
        __syncthreads();              // cur(ch) raw ready (prologue or prefetch)

        // ---- B1: per-column LN stats, wave-parallel (8 waves x shfl tree) ----
        for (int col = wv; col < 33; col += 8) {
            float x = cur[lane][col];
            float s1 = x, s2 = x * x;
            #pragma unroll
            for (int off = 32; off > 0; off >>= 1) {
                s1 += __shfl_xor(s1, off, 64);
                s2 += __shfl_xor(s2, off, 64);
            }
            if (lane == 0) {
                float mu  = s1 * (1.0f / 64.0f);
                float var = s2 * (1.0f / 64.0f) - mu * mu;
                smu[col]  = mu;
                sinv[col] = rsqrtf(fmaxf(var, 0.0f) + EPS);
            }
        }
        __syncthreads();

        // ---- B2: normalize in place, raw copy to sxr fused ----
        #pragma unroll
        for (int k = 0; k < 5; ++k) {
            int idx = tid + k * 512;
            if (idx < 64 * 33) {
                int cc = idx / 33, i = idx - cc * 33;
                float x = cur[cc][i];
                if (i < 32) sxr[cc][i] = x;
                cur[cc][i] = (x - smu[i]) * sinv[i] * sgam[cc] + sbet[cc];
            }
        }
        __syncthreads();

        // ---- gate p1: fw1t[m][t] ----
        {
            const int m = tid & 31, tg2 = tid >> 5;   // tg2 in [0,16)
            float a0 = 0.0f, a1 = 0.0f;
            for (int cc = 0; cc < 64; ++cc) {
                const float w0 = Wg1[(2*cc)*32 + m], w1 = Wg1[(2*cc+1)*32 + m];
                a0 += cur[cc][tg2]      * w0 + cur[cc][tg2 + 1]  * w1;
                a1 += cur[cc][tg2 + 16] * w0 + cur[cc][tg2 + 17] * w1;
            }
            fw1t[m][tg2] = a0; fw1t[m][tg2 + 16] = a1;
        }
        __syncthreads();

        // ---- gate p2: per (col d, t-half) cumsum with carry -> erun/egl ----
        float erunp[16], erunm[16];   // exp(+gc), exp(-gc) for own t-half
        {
            const int t0 = th * 16;
            float acc2[16];
            #pragma unroll
            for (int t = 0; t < 16; ++t) acc2[t] = 0.0f;
            for (int mm = 0; mm < 32; ++mm) {
                const float w = Wg2[mm * 256 + d];
                #pragma unroll
                for (int i = 0; i < 4; ++i) {
                    float4 f4 = *(const float4*)&fw1t[mm][t0 + 4 * i];
                    acc2[4*i+0] += f4.x * w; acc2[4*i+1] += f4.y * w;
                    acc2[4*i+2] += f4.z * w; acc2[4*i+3] += f4.w * w;
                }
            }
            float r = 0.0f;
            #pragma unroll
            for (int t = 0; t < 16; ++t) {
                if ((l0 + t0 + t) < L) r += logsig(acc2[t]) * (1.0f / 32.0f);
                acc2[t] = r;                    // reuse as cumsum store
            }
            if (th == 0) gcarry[d] = r;
            __syncthreads();
            const float c = (th == 0) ? 0.0f : gcarry[d];
            #pragma unroll
            for (int t = 0; t < 16; ++t) {
                float run = c + acc2[t];
                erunp[t] = __expf(run);
                erunm[t] = __expf(-run);
            }
            if (th == 1) egl[d] = erunp[15];
        }

        // ---- C: projections; (q,k) fused then v; gate folded at store ----
        {
            const int t0 = th * 16;
            float aq[16], ak[16];
            #pragma unroll
            for (int t = 0; t < 16; ++t) { aq[t] = 0.0f; ak[t] = 0.0f; }
            for (int cc = 0; cc < 64; ++cc) {
                float col[17];
                #pragma unroll
                for (int i = 0; i < 4; ++i) {
                    float4 c4 = *(const float4*)&cur[cc][t0 + 4 * i];
                    col[4*i] = c4.x; col[4*i+1] = c4.y; col[4*i+2] = c4.z; col[4*i+3] = c4.w;
                }
                col[16] = cur[cc][t0 + 16];
                const float wq0 = Wq[(2*cc)*256 + d], wq1 = Wq[(2*cc+1)*256 + d];
                const float wk0 = Wk[(2*cc)*256 + d], wk1 = Wk[(2*cc+1)*256 + d];
                #pragma unroll
                for (int t = 0; t < 16; ++t) {
                    aq[t] += col[t] * wq0 + col[t+1] * wq1;
                    ak[t] += col[t] * wk0 + col[t+1] * wk1;
                }
            }
            #pragma unroll
            for (int t = 0; t < 16; ++t) {
                bool valid = (l0 + t0 + t) < L;
                qf[t0 + t][d] = valid ? aq[t] * 0.125f * erunp[t] : 0.0f;
                kf[t0 + t][d] = valid ? ak[t] * erunm[t] : 0.0f;
            }
        }
        {
            const int t0 = th * 16;
            float av[16];
            #pragma unroll
            for (int t = 0; t < 16; ++t) av[t] = 0.0f;
            for (int cc = 0; cc < 64; ++cc) {
                float col[17];
                #pragma unroll
                for (int i = 0; i < 4; ++i) {
                    float4 c4 = *(const float4*)&cur[cc][t0 + 4 * i];
                    col[4*i] = c4.x; col[4*i+1] = c4.y; col[4*i+2] = c4.z; col[4*i+3] = c4.w;
                }
                col[16] = cur[cc][t0 + 16];
                const float wv0 = Wv[(2*cc)*256 + d], wv1 = Wv[(2*cc+1)*256 + d];
                #pragma unroll
                for (int t = 0; t < 16; ++t) av[t] += col[t] * wv0 + col[t+1] * wv1;
            }
            #pragma unroll
            for (int t = 0; t < 16; ++t)
                voc[t0 + t][d] = ((l0 + t0 + t) < L) ? av[t] : 0.0f;
        }
        __syncthreads();

        // ---- F: attention; 2 waves per head ----
        const int base = h * 64;
        float vcol[32];
        #pragma unroll
        for (int t = 0; t < 32; ++t) vcol[t] = voc[t][base + lane];

        // F1: triangular scores, 128 lanes per head
        for (int pi = lane + 64 * kh; pi < 528; pi += 128) {
            float fpi = (float)pi;
            int t = (int)((sqrtf(8.0f * fpi + 1.0f) - 1.0f) * 0.5f);
            if (((t + 1) * (t + 2)) / 2 <= pi) ++t;
            if ((t * (t + 1)) / 2 > pi) --t;
            int s = pi - (t * (t + 1)) / 2;
            float a = 0.0f;
            #pragma unroll
            for (int ii = 0; ii < 16; ++ii) {
                int i = (ii + lane) & 15;
                float4 q4 = *(const float4*)&qf[t][base + 4 * i];
                float4 k4 = *(const float4*)&kf[s][base + 4 * i];
                a += q4.x*k4.x + q4.y*k4.y + q4.z*k4.z + q4.w*k4.w;
            }
            Ats[h * 1152 + t * 36 + s] = a;
        }
        __syncthreads();   // A: Ats ready; all vcol snapshots done (voc dead as v)

        // F2a: kh1 writes o_inter partial (vs pre-update S rows 32..63) into voc
        if (kh == 1) {
            #pragma unroll
            for (int t = 0; t < 32; ++t) {
                float oe = 0.0f;
                #pragma unroll
                for (int i = 0; i < 8; ++i) {
                    float4 q4 = *(const float4*)&qf[t][base + 32 + 4 * i];
                    oe += q4.x*S[4*i] + q4.y*S[4*i+1] + q4.z*S[4*i+2] + q4.w*S[4*i+3];
                }
                voc[t][base + lane] = oe;
            }
        }
        __syncthreads();   // B: oe1 partials in voc

        if (kh == 0) {
            // F2b: o = oe0 + oe1 + o_intra, RMS-norm, final o into voc
            #pragma unroll
            for (int t = 0; t < 32; ++t) {
                float ot = voc[t][base + lane];
                #pragma unroll
                for (int i = 0; i < 8; ++i) {
                    float4 q4 = *(const float4*)&qf[t][base + 4 * i];
                    ot += q4.x*S[4*i] + q4.y*S[4*i+1] + q4.z*S[4*i+2] + q4.w*S[4*i+3];
                }
                const float* arow = &Ats[h * 1152 + t * 36];
                #pragma unroll
                for (int s4 = 0; s4 + 4 <= t + 1; s4 += 4) {
                    float4 a4 = *(const float4*)&arow[s4];
                    ot += a4.x*vcol[s4] + a4.y*vcol[s4+1] + a4.z*vcol[s4+2] + a4.w*vcol[s4+3];
                }
                #pragma unroll
                for (int s = (t + 1) & ~3; s <= t; ++s) ot += arow[s] * vcol[s];
                float ss = ot * ot;
                #pragma unroll
                for (int off = 32; off > 0; off >>= 1) ss += __shfl_xor(ss, off, 64);
                voc[t][base + lane] = ot * rsqrtf(ss * (1.0f / 64.0f) + EPS) * gnv;
            }
        } else {
            // kh1: F4 state update rows 32..63 (overlaps kh0's F2b)
            const int kb = base + 32;
            #pragma unroll
            for (int i = 0; i < 8; ++i) {
                float s0 = 0.0f, s1 = 0.0f, s2 = 0.0f, s3 = 0.0f;
                #pragma unroll
                for (int t = 0; t < 32; ++t) {
                    float4 k4 = *(const float4*)&kf[t][kb + 4 * i];
                    const float vt = vcol[t];
                    s0 += k4.x * vt; s1 += k4.y * vt; s2 += k4.z * vt; s3 += k4.w * vt;
                }
                S[4*i+0] = egl[kb + 4*i+0] * (S[4*i+0] + s0);
                S[4*i+1] = egl[kb + 4*i+1] * (S[4*i+1] + s1);
                S[4*i+2] = egl[kb + 4*i+2] * (S[4*i+2] + s2);
                S[4*i+3] = egl[kb + 4*i+3] * (S[4*i+3] + s3);
            }
        }
        __syncthreads();   // C: final o in voc; kh0 may now update S

        if (kh == 0) {
            // F4 state update rows 0..31 (overlaps kh1's half of G)
            const int kb = base;
            #pragma unroll
            for (int i = 0; i < 8; ++i) {
                float s0 = 0.0f, s1 = 0.0f, s2 = 0.0f, s3 = 0.0f;
                #pragma unroll
                for (int t = 0; t < 32; ++t) {
                    float4 k4 = *(const float4*)&kf[t][kb + 4 * i];
                    const float vt = vcol[t];
                    s0 += k4.x * vt; s1 += k4.y * vt; s2 += k4.z * vt; s3 += k4.w * vt;
                }
                S[4*i+0] = egl[kb + 4*i+0] * (S[4*i+0] + s0);
                S[4*i+1] = egl[kb + 4*i+1] * (S[4*i+1] + s1);
                S[4*i+2] = egl[kb + 4*i+2] * (S[4*i+2] + s2);
                S[4*i+3] = egl[kb + 4*i+3] * (S[4*i+3] + s3);
            }
        }

        // ---- G: r = f @ Wr ; voc *= silu(r) ----
        {
            const int t0 = th * 16;
            float ar[16];
            #pragma unroll
            for (int t = 0; t < 16; ++t) ar[t] = 0.0f;
            for (int cc = 0; cc < 64; ++cc) {
                float col[17];
                #pragma unroll
                for (int i = 0; i < 4; ++i) {
                    float4 c4 = *(const float4*)&cur[cc][t0 + 4 * i];
                    col[4*i] = c4.x; col[4*i+1] = c4.y; col[4*i+2] = c4.z; col[4*i+3] = c4.w;
                }
                col[16] = cur[cc][t0 + 16];
                const float w0 = Wr[(2*cc)*256 + d], w1 = Wr[(2*cc+1)*256 + d];
                #pragma unroll
                for (int t = 0; t < 16; ++t) ar[t] += col[t] * w0 + col[t+1] * w1;
            }
            #pragma unroll
            for (int t = 0; t < 16; ++t) {
                const float r = ar[t];
                voc[t0 + t][d] *= r / (1.0f + __expf(-r));
            }
        }
        __syncthreads();   // S_G: voc = o*silu(r); cur slab now dead

        // ---- A': issue next-chunk slab loads NOW (latency hides under H;
        //      the compiler's vmcnt(0)-at-barrier drain lands at S_H) ----
        float pre[5];
        if (pf) {
            const int l0n = l0 + 32;
            #pragma unroll
            for (int k = 0; k < 5; ++k) {
                int idx = tid + k * 512;
                if (idx < 64 * 33) {
                    int cc = idx / 33, i = idx - cc * 33;
                    int p  = l0n + i; if (p > SLEN - 1) p = SLEN - 1;
                    pre[k] = src[cbase + cc * 32768 + p * PSTRIDE];
                }
            }
        }

        // ---- H: gdec = oc @ Wo ; thread = (m2 in [0,64), 2 cols, 4 rows) ----
        // (gdec overlays Ats: Ats last read was F2b, two barriers ago)
        {
            const int m2  = tid & 63;
            const int tg4 = tid >> 6;        // 0..7 -> rows tg4*4..+3
            float accA[4] = {0,0,0,0}, accB[4] = {0,0,0,0};
            for (int j = 0; j < 256; j += 4) {
                float wA0 = Wo[(j+0)*128 + m2],      wB0 = Wo[(j+0)*128 + m2 + 64];
                float wA1 = Wo[(j+1)*128 + m2],      wB1 = Wo[(j+1)*128 + m2 + 64];
                float wA2 = Wo[(j+2)*128 + m2],      wB2 = Wo[(j+2)*128 + m2 + 64];
                float wA3 = Wo[(j+3)*128 + m2],      wB3 = Wo[(j+3)*128 + m2 + 64];
                #pragma unroll
                for (int i = 0; i < 4; ++i) {
                    float4 o4 = *(const float4*)&voc[tg4 * 4 + i][j];
                    accA[i] += o4.x*wA0 + o4.y*wA1 + o4.z*wA2 + o4.w*wA3;
                    accB[i] += o4.x*wB0 + o4.y*wB1 + o4.z*wB2 + o4.w*wB3;
                }
            }
            #pragma unroll
            for (int i = 0; i < 4; ++i) {
                gdec[(tg4 * 4 + i) * 132 + m2]      = accA[i];
                gdec[(tg4 * 4 + i) * 132 + m2 + 64] = accB[i];
            }
        }
        __syncthreads();   // S_H: gdec ready (prefetch loads drained here)

        // ---- A'': write prefetched slab into nxt (loads returned during H;
        //      nxt untouched until next chunk's loop-top barrier) ----
        if (pf) {
            #pragma unroll
            for (int k = 0; k < 5; ++k) {
                int idx = tid + k * 512;
                if (idx < 64 * 33) {
                    int cc = idx / 33, i = idx - cc * 33;
                    nxt[cc][i] = pre[k];
                }
            }
        }

        // ---- I: deconv1d (K=2) + bias + residual (from sxr) + store ----
        {
            const int o  = lane;
            const int pg = wv;               // 0..7 -> rows pg*4..+3
            const float2* ctw2 = (const float2*)ctw;   // [cin][o] -> (w_k0, w_k1)
            float acc4[4] = {0,0,0,0};
            for (int c4 = 0; c4 < 128; c4 += 4) {
                float2 w0 = ctw2[(c4+0)*64 + o];
                float2 w1 = ctw2[(c4+1)*64 + o];
                float2 w2 = ctw2[(c4+2)*64 + o];
                float2 w3 = ctw2[(c4+3)*64 + o];
                float4 r[5];
                r[0] = (pg == 0) ? *(const float4*)&gprevs[c4]
                                 : *(const float4*)&gdec[(pg*4 - 1) * 132 + c4];
                #pragma unroll
                for (int j = 0; j < 4; ++j)
                    r[j+1] = *(const float4*)&gdec[(pg*4 + j) * 132 + c4];
                #pragma unroll
                for (int i = 0; i < 4; ++i) {
                    acc4[i] += r[i+1].x*w0.x + r[i].x*w0.y
                             + r[i+1].y*w1.x + r[i].y*w1.y
                             + r[i+1].z*w2.x + r[i].z*w2.y
                             + r[i+1].w*w3.x + r[i].w*w3.y;
                }
            }
            #pragma unroll
            for (int i = 0; i < 4; ++i) {
                const int tl = pg * 4 + i;
                const int oi = cbase + o * 32768 + (l0 + tl) * PSTRIDE;
                out[oi] = acc4[i] + bias + sxr[o][tl];
            }
        }
        __syncthreads();
        if (tid < 128) gprevs[tid] = gdec[31 * 132 + tid];
    }
}

extern "C" void kernel_launch(void* const* d_in, const int* in_sizes, int n_in,
                              void* d_out, int out_size, void* d_ws, size_t ws_size,
                              hipStream_t stream)
{
    const float* x = (const float*)d_in[0];
    float* y = (float*)d_ws;     // intra output: 4*64*256*128 fp32
    float* z = (float*)d_out;

    gla_pass<128, 1><<<dim3(1024), dim3(512), 0, stream>>>(
        x, y,
        (const float*)d_in[2],  (const float*)d_in[3],  (const float*)d_in[4],
        (const float*)d_in[5],  (const float*)d_in[6],  (const float*)d_in[7],
        (const float*)d_in[8],  (const float*)d_in[9],  (const float*)d_in[10],
        (const float*)d_in[11], (const float*)d_in[12], (const float*)d_in[13]);

    gla_pass<256, 128><<<dim3(512), dim3(512), 0, stream>>>(
        y, z,
        (const float*)d_in[14], (const float*)d_in[15], (const float*)d_in[16],
        (const float*)d_in[17], (const float*)d_in[18], (const float*)d_in[19],
        (const float*)d_in[20], (const float*)d_in[21], (const float*)d_in[22],
        (const float*)d_in[23], (const float*)d_in[24], (const float*)d_in[25]);
}